// Round 14
// baseline (351.514 us; speedup 1.0000x reference)
//
#include <hip/hip_runtime.h>
#include <hip/hip_bf16.h>
#include <math.h>

#define HID 128

typedef unsigned short u16;
typedef __attribute__((ext_vector_type(8))) short bfrag;      // 8 bf16 (4 VGPRs)
typedef __attribute__((ext_vector_type(4))) float f32x4;      // MFMA C/D
typedef __attribute__((ext_vector_type(8))) unsigned short u16x8;
typedef __attribute__((ext_vector_type(4))) unsigned short u16x4;

// saturates correctly without clamp: v>>0 -> e=inf -> rcp=0 -> 1; v<<0 -> e~0 -> -1
__device__ __forceinline__ float fast_tanh(float v) {
    float e = __expf(2.0f * v);
    float r = __builtin_amdgcn_rcpf(e + 1.0f);
    return 1.0f - 2.0f * r;
}

// fp32 -> bf16 via HW convert (compiler pairs these into v_cvt_pk_bf16_f32)
__device__ __forceinline__ u16 f2b(float f) {
    __hip_bfloat16 h = __float2bfloat16(f);
    return *(u16*)&h;
}
__device__ __forceinline__ float bits2f(unsigned u) {
    union { unsigned u; float f; } v; v.u = u; return v.f;
}
__device__ __forceinline__ float b2f(u16 b) {
    return bits2f(((unsigned)b) << 16);
}

// ---------------- merged prep: x->bf16 | weights->k-major bf16 | hist ----------------
__global__ void __launch_bounds__(256) prep_combo(
    const float* __restrict__ x, u16* __restrict__ xb,
    const float* __restrict__ w1, const float* __restrict__ fh1,
    const float* __restrict__ w2, const float* __restrict__ fh2,
    const float* __restrict__ l1, const float* __restrict__ l2,
    const float* __restrict__ l3, const float* __restrict__ l4,
    u16* __restrict__ w1t, u16* __restrict__ fh1t,
    u16* __restrict__ w2t, u16* __restrict__ fh2t,
    u16* __restrict__ l1t, u16* __restrict__ l2t,
    u16* __restrict__ l3t, u16* __restrict__ l4t,
    const int* __restrict__ est, int* __restrict__ cnt, int E, int nxb)
{
    int b = blockIdx.x, t = threadIdx.x;
    if (b < nxb) {
        int i = b * 256 + t;
        const float4 v0 = *(const float4*)(x + (size_t)i * 8);
        const float4 v1 = *(const float4*)(x + (size_t)i * 8 + 4);
        u16x8 o = { f2b(v0.x), f2b(v0.y), f2b(v0.z), f2b(v0.w),
                    f2b(v1.x), f2b(v1.y), f2b(v1.z), f2b(v1.w) };
        *(u16x8*)(xb + (size_t)i * 8) = o;
        return;
    }
    b -= nxb;
    if (b < 640) {
        const float* src; u16* dst; int K;
        if (b < 256) {
            K = 256;
            if (b < 128) { src = w1;  dst = w1t; }
            else         { src = fh1; dst = fh1t; b -= 128; }
        } else {
            K = 128;
            int s = (b - 256) >> 6; b = (b - 256) & 63;
            switch (s) {
                case 0:  src = w2;  dst = w2t;  break;
                case 1:  src = fh2; dst = fh2t; break;
                case 2:  src = l1;  dst = l1t;  break;
                case 3:  src = l2;  dst = l2t;  break;
                case 4:  src = l3;  dst = l3t;  break;
                default: src = l4;  dst = l4t;  break;
            }
        }
        int idx = b * 256 + t;
        int k = idx >> 7, n = idx & 127;
        dst[(size_t)n * K + k] = f2b(src[(size_t)k * 128 + n]);
        return;
    }
    b -= 640;
    int e = b * 256 + t;
    if (e < E) atomicAdd(&cnt[est[e]], 1);
}

// ---------------- CSR build: scan / reorder(sorted edge arrays) ----------------
__global__ void __launch_bounds__(256) scan1(const int* __restrict__ cnt,
                                             int* __restrict__ scanout,
                                             int* __restrict__ partial, int N) {
    __shared__ int s[256];
    int t = threadIdx.x, b = blockIdx.x, i = b * 256 + t;
    int v = (i < N) ? cnt[i] : 0;
    s[t] = v; __syncthreads();
#pragma unroll
    for (int d = 1; d < 256; d <<= 1) {
        int add = (t >= d) ? s[t - d] : 0;
        __syncthreads();
        s[t] += add;
        __syncthreads();
    }
    if (i < N) scanout[i] = s[t] - v;
    if (t == 255) partial[b] = s[255];
}

__global__ void __launch_bounds__(512) scan2(int* __restrict__ partial, int NB) {
    __shared__ int s[512];
    int t = threadIdx.x;
    int v = (t < NB) ? partial[t] : 0;
    s[t] = v; __syncthreads();
#pragma unroll
    for (int d = 1; d < 512; d <<= 1) {
        int add = (t >= d) ? s[t - d] : 0;
        __syncthreads();
        s[t] += add;
        __syncthreads();
    }
    if (t < NB) partial[t] = s[t] - v;
}

__global__ void __launch_bounds__(256) scan3(const int* __restrict__ scanout,
                                             const int* __restrict__ partial,
                                             int* __restrict__ offs,
                                             int* __restrict__ cur, int N, int E) {
    int t = threadIdx.x, b = blockIdx.x, i = b * 256 + t;
    if (i < N) { int o = scanout[i] + partial[b]; offs[i] = o; cur[i] = o; }
    if (i == 0) offs[N] = E;
}

__global__ void __launch_bounds__(256) reorder_kernel(const int* __restrict__ est,
                                                      const int* __restrict__ eend,
                                                      int* __restrict__ cur,
                                                      int* __restrict__ est_s,
                                                      int* __restrict__ eend_s, int E) {
    int e = blockIdx.x * 256 + threadIdx.x;
    if (e < E) {
        int s = est[e];
        int p = atomicAdd(&cur[s], 1);
        est_s[p]  = s;
        eend_s[p] = eend[e];
    }
}

// ---------------- GEMM helpers ----------------
template<int KD>
__device__ __forceinline__ void gemm_k(const u16* sbuf, const u16* __restrict__ wt,
                                       int w, int l16, int l4g, f32x4 (&acc)[2][2]) {
    const int RS = KD * 2;
#pragma unroll
    for (int k0 = 0; k0 < KD; k0 += 32) {
        const int kb = k0 * 2 + l4g * 16;
        bfrag a0 = *(const bfrag*)((const char*)sbuf +
                    (unsigned)((l16 * RS + kb) ^ ((l16 & 7) << 4)));
        bfrag a1 = *(const bfrag*)((const char*)sbuf +
                    (unsigned)(((16 + l16) * RS + kb) ^ ((l16 & 7) << 4)));
        bfrag b0 = *(const bfrag*)((const char*)wt + (size_t)(32 * w + l16) * RS + kb);
        bfrag b1 = *(const bfrag*)((const char*)wt + (size_t)(32 * w + 16 + l16) * RS + kb);
        acc[0][0] = __builtin_amdgcn_mfma_f32_16x16x32_bf16(a0, b0, acc[0][0], 0, 0, 0);
        acc[0][1] = __builtin_amdgcn_mfma_f32_16x16x32_bf16(a0, b1, acc[0][1], 0, 0, 0);
        acc[1][0] = __builtin_amdgcn_mfma_f32_16x16x32_bf16(a1, b0, acc[1][0], 0, 0, 0);
        acc[1][1] = __builtin_amdgcn_mfma_f32_16x16x32_bf16(a1, b1, acc[1][1], 0, 0, 0);
    }
}

// Swapped orientation: D[row=out-ch (mi,rg)][col=row-in-tile (ni,l16)]
template<int KD>
__device__ __forceinline__ void gemm_sw(const u16* act, const u16* __restrict__ wt,
                                        int w, int l16, int l4g, f32x4 (&acc)[2][2]) {
    const int RS = KD * 2;
#pragma unroll
    for (int k0 = 0; k0 < KD; k0 += 32) {
        const int kb = k0 * 2 + l4g * 16;
        bfrag wa0 = *(const bfrag*)((const char*)wt + (size_t)(32 * w + l16) * RS + kb);
        bfrag wa1 = *(const bfrag*)((const char*)wt + (size_t)(32 * w + 16 + l16) * RS + kb);
        bfrag be0 = *(const bfrag*)((const char*)act +
                    (unsigned)((l16 * RS + kb) ^ ((l16 & 7) << 4)));
        bfrag be1 = *(const bfrag*)((const char*)act +
                    (unsigned)(((16 + l16) * RS + kb) ^ ((l16 & 7) << 4)));
        acc[0][0] = __builtin_amdgcn_mfma_f32_16x16x32_bf16(wa0, be0, acc[0][0], 0, 0, 0);
        acc[0][1] = __builtin_amdgcn_mfma_f32_16x16x32_bf16(wa0, be1, acc[0][1], 0, 0, 0);
        acc[1][0] = __builtin_amdgcn_mfma_f32_16x16x32_bf16(wa1, be0, acc[1][0], 0, 0, 0);
        acc[1][1] = __builtin_amdgcn_mfma_f32_16x16x32_bf16(wa1, be1, acc[1][1], 0, 0, 0);
    }
}

// ---------------- edge kernel: persistent, single-barrier pipeline ----------------
// Round-14 change: only HALF of w1 is register-hoisted (wa10); the wa11
// fragments are read from global (L2-resident 64 KB) inside the loop. This
// cuts ~32 arch VGPRs so 3 blocks/CU can fit (LDS 53.76 KB x 3 <= 160 KB).
// Grid is 768 to exploit 3 resident blocks (round-9 showed grid>residency
// costs a tail; counters adjudicate via OccupancyPercent).
__global__ void __launch_bounds__(256, 2)
egc_edge_csr(const u16* __restrict__ xb, const float* __restrict__ pos,
             const int* __restrict__ est_s, const int* __restrict__ eend_s,
             const u16* __restrict__ w1t, const float* __restrict__ w1last,
             const float* __restrict__ b1, const u16* __restrict__ w2t,
             const float* __restrict__ b2, const float* __restrict__ fw,
             const float* __restrict__ fb, u16* __restrict__ g,
             float* __restrict__ ev, int n_tiles)
{
    __shared__ __attribute__((aligned(16))) u16 a_sh[2][32 * 256];  // 32 KB dbuf, swz
    __shared__ __attribute__((aligned(16))) u16 m1_sh[2][32 * 128]; // 16 KB dbuf, swz
    __shared__ float red[2][32][17];                                // gate partials dbuf
    __shared__ float dist_l[2][32];

    const int t = threadIdx.x, lane = t & 63, w = t >> 6;
    const int l16 = lane & 15, l4g = lane >> 4;
    const unsigned swz = (unsigned)((l16 & 7) << 4);

    bfrag wa10[8], w2f0[4], w2f1[4];
#pragma unroll
    for (int i = 0; i < 8; ++i) {
        int kb = i * 64 + l4g * 16;
        wa10[i] = *(const bfrag*)((const char*)w1t + (size_t)(32 * w + l16) * 512 + kb);
    }
#pragma unroll
    for (int i = 0; i < 4; ++i) {
        int kb = i * 64 + l4g * 16;
        w2f0[i] = *(const bfrag*)((const char*)w2t + (size_t)(32 * w + l16) * 256 + kb);
        w2f1[i] = *(const bfrag*)((const char*)w2t + (size_t)(32 * w + 16 + l16) * 256 + kb);
    }
    const char* w1row1 = (const char*)w1t + (size_t)(32 * w + 16 + l16) * 512;
    float w1l_r[2][4], b1_r[2][4], b2_r[2][4], fw_r[2][4];
#pragma unroll
    for (int mi = 0; mi < 2; ++mi)
#pragma unroll
        for (int rg = 0; rg < 4; ++rg) {
            int n = 32 * w + 16 * mi + l4g * 4 + rg;
            w1l_r[mi][rg] = w1last[n];
            b1_r[mi][rg]  = b1[n];
            b2_r[mi][rg]  = b2[n];
            fw_r[mi][rg]  = fw[n];
        }
    const float fbv = fb[0];

    float4 sv0, sv1, sv2, sv3;
    float pax = 0, pay = 0, paz = 0, pbx = 0, pby = 0, pbz = 0;

#define EDGE_ISSUE(TILE) do {                                                  \
        int e0_ = (TILE) * 32;                                                 \
        { int f_ = t;       int e_ = f_ >> 5, q_ = f_ & 31; int ge_ = e0_ + e_;\
          int nd_ = (q_ < 16) ? est_s[ge_] : eend_s[ge_];                      \
          sv0 = *(const float4*)(xb + (size_t)nd_ * 128 + (q_ & 15) * 8); }    \
        { int f_ = t + 256; int e_ = f_ >> 5, q_ = f_ & 31; int ge_ = e0_ + e_;\
          int nd_ = (q_ < 16) ? est_s[ge_] : eend_s[ge_];                      \
          sv1 = *(const float4*)(xb + (size_t)nd_ * 128 + (q_ & 15) * 8); }    \
        { int f_ = t + 512; int e_ = f_ >> 5, q_ = f_ & 31; int ge_ = e0_ + e_;\
          int nd_ = (q_ < 16) ? est_s[ge_] : eend_s[ge_];                      \
          sv2 = *(const float4*)(xb + (size_t)nd_ * 128 + (q_ & 15) * 8); }    \
        { int f_ = t + 768; int e_ = f_ >> 5, q_ = f_ & 31; int ge_ = e0_ + e_;\
          int nd_ = (q_ < 16) ? est_s[ge_] : eend_s[ge_];                      \
          sv3 = *(const float4*)(xb + (size_t)nd_ * 128 + (q_ & 15) * 8); }    \
        if (t < 32) {                                                          \
            int ge_ = e0_ + t;                                                 \
            int a_ = est_s[ge_], b_ = eend_s[ge_];                             \
            pax = pos[a_ * 3]; pay = pos[a_ * 3 + 1]; paz = pos[a_ * 3 + 2];   \
            pbx = pos[b_ * 3]; pby = pos[b_ * 3 + 1]; pbz = pos[b_ * 3 + 2];   \
        }                                                                      \
    } while (0)

#define EDGE_COMMIT(BUF) do {                                                  \
        { int f_ = t;       int e_ = f_ >> 5, q_ = f_ & 31;                    \
          unsigned by_ = (unsigned)(e_ * 512 + q_ * 16) ^ (unsigned)((e_ & 7) << 4); \
          *(float4*)((char*)a_sh[BUF] + by_) = sv0; }                          \
        { int f_ = t + 256; int e_ = f_ >> 5, q_ = f_ & 31;                    \
          unsigned by_ = (unsigned)(e_ * 512 + q_ * 16) ^ (unsigned)((e_ & 7) << 4); \
          *(float4*)((char*)a_sh[BUF] + by_) = sv1; }                          \
        { int f_ = t + 512; int e_ = f_ >> 5, q_ = f_ & 31;                    \
          unsigned by_ = (unsigned)(e_ * 512 + q_ * 16) ^ (unsigned)((e_ & 7) << 4); \
          *(float4*)((char*)a_sh[BUF] + by_) = sv2; }                          \
        { int f_ = t + 768; int e_ = f_ >> 5, q_ = f_ & 31;                    \
          unsigned by_ = (unsigned)(e_ * 512 + q_ * 16) ^ (unsigned)((e_ & 7) << 4); \
          *(float4*)((char*)a_sh[BUF] + by_) = sv3; }                          \
        if (t < 32) {                                                          \
            float dx_ = pax - pbx, dy_ = pay - pby, dz_ = paz - pbz;           \
            dx_ *= dx_; dy_ *= dy_; dz_ *= dz_;                                \
            dist_l[BUF][t] = sqrtf(dx_ * dx_ + dy_ * dy_ + dz_ * dz_);         \
        }                                                                      \
    } while (0)

    // GEMM1: a_sh[p] -> m1_sh[p] (tanh + dist rank-1); wa11 read from global L2
    auto do_gemm1 = [&](int p) {
        f32x4 acc[2][2] = {};
#pragma unroll
        for (int i = 0; i < 8; ++i) {
            int kb = i * 64 + l4g * 16;
            bfrag wa11 = *(const bfrag*)(w1row1 + kb);
            bfrag be0 = *(const bfrag*)((const char*)a_sh[p] +
                        ((unsigned)(l16 * 512 + kb) ^ swz));
            bfrag be1 = *(const bfrag*)((const char*)a_sh[p] +
                        ((unsigned)((16 + l16) * 512 + kb) ^ swz));
            acc[0][0] = __builtin_amdgcn_mfma_f32_16x16x32_bf16(wa10[i], be0, acc[0][0], 0, 0, 0);
            acc[0][1] = __builtin_amdgcn_mfma_f32_16x16x32_bf16(wa10[i], be1, acc[0][1], 0, 0, 0);
            acc[1][0] = __builtin_amdgcn_mfma_f32_16x16x32_bf16(wa11, be0, acc[1][0], 0, 0, 0);
            acc[1][1] = __builtin_amdgcn_mfma_f32_16x16x32_bf16(wa11, be1, acc[1][1], 0, 0, 0);
        }
        float de0 = dist_l[p][l16];
        float de1 = dist_l[p][16 + l16];
#pragma unroll
        for (int mi = 0; mi < 2; ++mi)
#pragma unroll
            for (int ni = 0; ni < 2; ++ni) {
                float de = ni ? de1 : de0;
                u16x4 pk;
#pragma unroll
                for (int rg = 0; rg < 4; ++rg) {
                    float v = fast_tanh(acc[mi][ni][rg] + de * w1l_r[mi][rg] + b1_r[mi][rg]);
                    pk[rg] = f2b(v);
                }
                unsigned byte = ((unsigned)((16 * ni + l16) * 256 +
                                 (32 * w + 16 * mi + l4g * 4) * 2)) ^ swz;
                *(u16x4*)((char*)m1_sh[p] + byte) = pk;
            }
    };

    // GEMM2: m1_sh[mp] -> g rows e0.., red[rp]
    auto do_gemm2 = [&](int e0, int rp, int mp) {
        f32x4 acc[2][2] = {};
#pragma unroll
        for (int i = 0; i < 4; ++i) {
            int kb = i * 64 + l4g * 16;
            bfrag me0 = *(const bfrag*)((const char*)m1_sh[mp] +
                        ((unsigned)(l16 * 256 + kb) ^ swz));
            bfrag me1 = *(const bfrag*)((const char*)m1_sh[mp] +
                        ((unsigned)((16 + l16) * 256 + kb) ^ swz));
            acc[0][0] = __builtin_amdgcn_mfma_f32_16x16x32_bf16(w2f0[i], me0, acc[0][0], 0, 0, 0);
            acc[0][1] = __builtin_amdgcn_mfma_f32_16x16x32_bf16(w2f0[i], me1, acc[0][1], 0, 0, 0);
            acc[1][0] = __builtin_amdgcn_mfma_f32_16x16x32_bf16(w2f1[i], me0, acc[1][0], 0, 0, 0);
            acc[1][1] = __builtin_amdgcn_mfma_f32_16x16x32_bf16(w2f1[i], me1, acc[1][1], 0, 0, 0);
        }
        float part0 = 0.0f, part1 = 0.0f;
#pragma unroll
        for (int mi = 0; mi < 2; ++mi)
#pragma unroll
            for (int ni = 0; ni < 2; ++ni) {
                u16x4 pk;
                float ps = 0.0f;
#pragma unroll
                for (int rg = 0; rg < 4; ++rg) {
                    float v = fast_tanh(acc[mi][ni][rg] + b2_r[mi][rg]);
                    ps += v * fw_r[mi][rg];
                    pk[rg] = f2b(v);
                }
                if (ni) part1 += ps; else part0 += ps;
                int dstrow = e0 + 16 * ni + l16;        // CSR position = sequential
                *(u16x4*)(g + (size_t)dstrow * 128 + (32 * w + 16 * mi + l4g * 4)) = pk;
            }
        red[rp][l16][w * 4 + l4g]      = part0;
        red[rp][16 + l16][w * 4 + l4g] = part1;
    };

    auto do_reduce = [&](int e0, int rp) {
        if (t < 32) {
            float s = 0.0f;
#pragma unroll
            for (int j = 0; j < 16; ++j) s += red[rp][t][j];
            ev[e0 + t] = fast_tanh(s + fbv);
        }
    };

    int t1 = blockIdx.x;            // GEMM1 tile this phase
    int t2 = -1, tr = -1;           // GEMM2 tile / reduce tile
    int pk = 0;
    EDGE_ISSUE(t1);
    EDGE_COMMIT(0);
    int tnext = t1 + gridDim.x;

    while (true) {
        __syncthreads();                                 // B1 (one per tile)
        if (tr >= 0) do_reduce(tr * 32, pk ^ 1);
        bool have_next = (tnext < n_tiles);
        if (have_next) EDGE_ISSUE(tnext);
        do_gemm1(pk);
        if (t2 >= 0) do_gemm2(t2 * 32, pk, pk ^ 1);
        if (have_next) EDGE_COMMIT(pk ^ 1);
        tr = t2; t2 = t1;
        if (!have_next) break;
        t1 = tnext; tnext += gridDim.x; pk ^= 1;
    }
    // drain: GEMM2 for the last tile (m1 in m1_sh[pk]), plus two final reduces
    __syncthreads();
    if (tr >= 0) do_reduce(tr * 32, pk);
    do_gemm2(t2 * 32, pk ^ 1, pk);
    __syncthreads();
    do_reduce(t2 * 32, pk ^ 1);
#undef EDGE_ISSUE
#undef EDGE_COMMIT
}

// ---------------- gather: half-wave per edge parity, 4 edges in flight ----------------
__global__ void __launch_bounds__(256, 8)
gather_seq(const u16* __restrict__ g, const float* __restrict__ ev,
           const int* __restrict__ offs, u16* __restrict__ m_i)
{
    const int lane = threadIdx.x & 63;
    const int half = lane >> 5;
    const int l32  = lane & 31;
    const int n = blockIdx.x * 4 + (threadIdx.x >> 6);
    const int beg = offs[n], end = offs[n + 1];
    float a0 = 0.0f, a1 = 0.0f, a2 = 0.0f, a3 = 0.0f;
    float b0 = 0.0f, b1 = 0.0f, b2 = 0.0f, b3 = 0.0f;
    int e = beg + half;
    for (; e + 3 < end; e += 4) {
        uint2 v0 = *(const uint2*)(g + (size_t)e * 128 + l32 * 4);
        uint2 v1 = *(const uint2*)(g + (size_t)(e + 2) * 128 + l32 * 4);
        float e0 = ev[e], e1 = ev[e + 2];
        a0 += e0 * bits2f(v0.x << 16);
        a1 += e0 * bits2f(v0.x & 0xFFFF0000u);
        a2 += e0 * bits2f(v0.y << 16);
        a3 += e0 * bits2f(v0.y & 0xFFFF0000u);
        b0 += e1 * bits2f(v1.x << 16);
        b1 += e1 * bits2f(v1.x & 0xFFFF0000u);
        b2 += e1 * bits2f(v1.y << 16);
        b3 += e1 * bits2f(v1.y & 0xFFFF0000u);
    }
    for (; e < end; e += 2) {
        uint2 v0 = *(const uint2*)(g + (size_t)e * 128 + l32 * 4);
        float e0 = ev[e];
        a0 += e0 * bits2f(v0.x << 16);
        a1 += e0 * bits2f(v0.x & 0xFFFF0000u);
        a2 += e0 * bits2f(v0.y << 16);
        a3 += e0 * bits2f(v0.y & 0xFFFF0000u);
    }
    a0 += b0; a1 += b1; a2 += b2; a3 += b3;
    a0 += __shfl_xor(a0, 32);
    a1 += __shfl_xor(a1, 32);
    a2 += __shfl_xor(a2, 32);
    a3 += __shfl_xor(a3, 32);
    if (half == 0) {
        uint2 o;
        o.x = (unsigned)f2b(a0) | ((unsigned)f2b(a1) << 16);
        o.y = (unsigned)f2b(a2) | ((unsigned)f2b(a3) << 16);
        *(uint2*)(m_i + (size_t)n * 128 + l32 * 4) = o;
    }
}

// ---------------- edge kernel, fallback atomic path (round-3, proven) ----------------
__global__ void __launch_bounds__(256, 3)
egc_edge_mfma(const u16* __restrict__ xb, const float* __restrict__ pos,
              const int* __restrict__ est, const int* __restrict__ eend,
              const u16* __restrict__ w1t, const float* __restrict__ w1last,
              const float* __restrict__ b1, const u16* __restrict__ w2t,
              const float* __restrict__ b2, const float* __restrict__ fw,
              const float* __restrict__ fb, float* __restrict__ m_i)
{
    __shared__ __attribute__((aligned(16))) u16 a_sh[32 * 256];
    __shared__ __attribute__((aligned(16))) u16 m1_sh[32 * 128];
    __shared__ float m2_sh[32][132];
    __shared__ float dist_l[32];
    __shared__ float ev_l[32];
    __shared__ int   st_l[32];

    const int t = threadIdx.x;
    const int e0 = blockIdx.x * 32;
    const int lane = t & 63;
    const int w = t >> 6;
    const int l16 = lane & 15, l4g = lane >> 4;

#pragma unroll
    for (int i = 0; i < 4; ++i) {
        int f = t + 256 * i;
        int e = f >> 5, q = f & 31;
        int ge = e0 + e;
        int node = (q < 16) ? est[ge] : eend[ge];
        float4 v = *(const float4*)(xb + (size_t)node * 128 + (q & 15) * 8);
        unsigned byte = (unsigned)(e * 512 + q * 16) ^ (unsigned)((e & 7) << 4);
        *(float4*)((char*)a_sh + byte) = v;
    }
    if (t < 32) {
        int ge = e0 + t;
        int a = est[ge], b = eend[ge];
        st_l[t] = a;
        float dx = pos[a * 3 + 0] - pos[b * 3 + 0];
        float dy = pos[a * 3 + 1] - pos[b * 3 + 1];
        float dz = pos[a * 3 + 2] - pos[b * 3 + 2];
        dx *= dx; dy *= dy; dz *= dz;
        dist_l[t] = sqrtf(dx * dx + dy * dy + dz * dz);
    }
    __syncthreads();

    {
        f32x4 acc[2][2] = {};
        gemm_k<256>(a_sh, w1t, w, l16, l4g, acc);
#pragma unroll
        for (int mi = 0; mi < 2; ++mi)
#pragma unroll
            for (int ni = 0; ni < 2; ++ni) {
                const int col = 32 * w + 16 * ni + l16;
                const float wl = w1last[col], bb = b1[col];
#pragma unroll
                for (int rg = 0; rg < 4; ++rg) {
                    const int row = 16 * mi + l4g * 4 + rg;
                    float v = fast_tanh(acc[mi][ni][rg] + dist_l[row] * wl + bb);
                    unsigned byte = (unsigned)((row * 256 + col * 2) ^ ((row & 7) << 4));
                    *(u16*)((char*)m1_sh + byte) = f2b(v);
                }
            }
    }
    __syncthreads();

    {
        f32x4 acc[2][2] = {};
        gemm_k<128>(m1_sh, w2t, w, l16, l4g, acc);
#pragma unroll
        for (int mi = 0; mi < 2; ++mi)
#pragma unroll
            for (int ni = 0; ni < 2; ++ni) {
                const int col = 32 * w + 16 * ni + l16;
                const float bb = b2[col];
#pragma unroll
                for (int rg = 0; rg < 4; ++rg) {
                    const int row = 16 * mi + l4g * 4 + rg;
                    m2_sh[row][col] = fast_tanh(acc[mi][ni][rg] + bb);
                }
            }
    }
    __syncthreads();

    if (t < 128) {
        int e = t >> 2, p = t & 3;
        float s = 0.0f;
#pragma unroll
        for (int k = 0; k < 32; ++k) s += m2_sh[e][p * 32 + k] * fw[p * 32 + k];
        s += __shfl_xor(s, 1);
        s += __shfl_xor(s, 2);
        if (p == 0) ev_l[e] = fast_tanh(s + fb[0]);
    }
    __syncthreads();

    {
        int e = t >> 3, l8 = t & 7;
        float ev = ev_l[e];
        size_t base = (size_t)st_l[e] * HID + l8;
#pragma unroll
        for (int i = 0; i < 16; ++i)
            unsafeAtomicAdd(m_i + base + 8 * i, ev * m2_sh[e][l8 + 8 * i]);
    }
}

// ---------------- node kernel: swapped-operand layers, register l5 head ----------------
#define NODE_LAYER_SW(SRC, KD, WT, BIAS, DST, ACT)                             \
    {                                                                          \
        f32x4 acc[2][2] = {};                                                  \
        gemm_sw<KD>(SRC, WT, w, l16, l4g, acc);                                \
        float bbr[2][4];                                                       \
        _Pragma("unroll")                                                      \
        for (int mi = 0; mi < 2; ++mi)                                         \
            _Pragma("unroll")                                                  \
            for (int rg = 0; rg < 4; ++rg)                                     \
                bbr[mi][rg] = (BIAS)[32 * w + 16 * mi + l4g * 4 + rg];         \
        _Pragma("unroll")                                                      \
        for (int mi = 0; mi < 2; ++mi)                                         \
            _Pragma("unroll")                                                  \
            for (int ni = 0; ni < 2; ++ni) {                                   \
                const int node = 16 * ni + l16;                                \
                const int ch = 32 * w + 16 * mi + l4g * 4;                     \
                u16x4 pk;                                                      \
                _Pragma("unroll")                                              \
                for (int rg = 0; rg < 4; ++rg) {                               \
                    float v = acc[mi][ni][rg] + bbr[mi][rg];                   \
                    ACT;                                                       \
                    pk[rg] = f2b(v);                                           \
                }                                                              \
                unsigned byte = ((unsigned)(node * 256 + ch * 2)) ^ swz;       \
                *(u16x4*)((char*)(DST) + byte) = pk;                           \
            }                                                                  \
    }

// MODE 0: CSR path — m_i is bf16. MODE 1: fallback — m_i is fp32.
// LDS 38.9 KB, 4 blocks/CU (round 12). Residual read from a_sh's x half
// (still intact when fh2 runs) — no global xf traffic.
template<int MODE>
__global__ void __launch_bounds__(256, 4)
egc_node_mfma(const u16* __restrict__ xb,
              const void* __restrict__ m_i,
              const u16* __restrict__ fh1t, const float* __restrict__ hb1,
              const u16* __restrict__ fh2t, const float* __restrict__ hb2,
              const u16* __restrict__ l1t, const float* __restrict__ l1b,
              const u16* __restrict__ l2t, const float* __restrict__ l2b,
              const u16* __restrict__ l3t, const float* __restrict__ l3b,
              const u16* __restrict__ l4t, const float* __restrict__ l4b,
              const float* __restrict__ l5w, const float* __restrict__ l5b,
              float* __restrict__ out)
{
    __shared__ __attribute__((aligned(16))) u16 a_sh[32 * 256];   // 16 KB
    __shared__ __attribute__((aligned(16))) u16 bA[32 * 128];     // 8 KB
    __shared__ __attribute__((aligned(16))) u16 bB[32 * 128];     // 8 KB
    __shared__ float red[32][3][17];                              // 6.4 KB l5 partials

    const int t = threadIdx.x;
    const int n0 = blockIdx.x * 32;
    const int lane = t & 63;
    const int w = t >> 6;
    const int l16 = lane & 15, l4g = lane >> 4;
    const unsigned swz = (unsigned)((l16 & 7) << 4);

#pragma unroll
    for (int i = 0; i < 2; ++i) {
        int f = t + 256 * i;
        int n = f >> 4, q = f & 15;
        float4 v = *(const float4*)(xb + (size_t)(n0 + n) * 128 + q * 8);
        unsigned byte = (unsigned)((n * 512 + q * 16) ^ ((n & 7) << 4));
        *(float4*)((char*)a_sh + byte) = v;
    }
    if (MODE == 0) {
#pragma unroll
        for (int i = 0; i < 2; ++i) {
            int f = t + 256 * i;
            int n = f >> 4, q = f & 15;
            float4 v = *(const float4*)((const u16*)m_i + (size_t)(n0 + n) * 128 + q * 8);
            unsigned byte = (unsigned)((n * 512 + 256 + q * 16) ^ ((n & 7) << 4));
            *(float4*)((char*)a_sh + byte) = v;
        }
    } else {
#pragma unroll
        for (int i = 0; i < 2; ++i) {
            int f = t + 256 * i;
            int n = f >> 4, q = f & 15;
            const float* src = (const float*)m_i + (size_t)(n0 + n) * 128 + q * 8;
            float4 v0 = *(const float4*)(src);
            float4 v1 = *(const float4*)(src + 4);
            u16x8 o = { f2b(v0.x), f2b(v0.y), f2b(v0.z), f2b(v0.w),
                        f2b(v1.x), f2b(v1.y), f2b(v1.z), f2b(v1.w) };
            unsigned byte = (unsigned)((n * 512 + 256 + q * 16) ^ ((n & 7) << 4));
            *(u16x8*)((char*)a_sh + byte) = o;
        }
    }
    __syncthreads();

    NODE_LAYER_SW(a_sh, 256, fh1t, hb1, bA, { v = fast_tanh(v); })
    __syncthreads();

    // fh2: K=128, + residual from a_sh's x half (bf16, swizzled 8 B read) -> bB
    {
        f32x4 acc[2][2] = {};
        gemm_sw<128>(bA, fh2t, w, l16, l4g, acc);
        float bbr[2][4];
#pragma unroll
        for (int mi = 0; mi < 2; ++mi)
#pragma unroll
            for (int rg = 0; rg < 4; ++rg)
                bbr[mi][rg] = hb2[32 * w + 16 * mi + l4g * 4 + rg];
#pragma unroll
        for (int mi = 0; mi < 2; ++mi)
#pragma unroll
            for (int ni = 0; ni < 2; ++ni) {
                const int node = 16 * ni + l16;
                const int ch = 32 * w + 16 * mi + l4g * 4;
                unsigned rb = ((unsigned)(node * 512 + ch * 2)) ^
                              ((unsigned)((node & 7) << 4));
                u16x4 xr = *(const u16x4*)((const char*)a_sh + rb);
                u16x4 pk;
                pk[0] = f2b(acc[mi][ni][0] + bbr[mi][0] + b2f(xr[0]));
                pk[1] = f2b(acc[mi][ni][1] + bbr[mi][1] + b2f(xr[1]));
                pk[2] = f2b(acc[mi][ni][2] + bbr[mi][2] + b2f(xr[2]));
                pk[3] = f2b(acc[mi][ni][3] + bbr[mi][3] + b2f(xr[3]));
                unsigned byte = ((unsigned)(node * 256 + ch * 2)) ^ swz;
                *(u16x4*)((char*)bB + byte) = pk;
            }
    }
    __syncthreads();

    NODE_LAYER_SW(bB, 128, l1t, l1b, bA, { v = v > 0.0f ? v : 0.01f * v; })
    __syncthreads();
    NODE_LAYER_SW(bA, 128, l2t, l2b, bB, { v = v > 0.0f ? v : 0.01f * v; })
    __syncthreads();
    NODE_LAYER_SW(bB, 128, l3t, l3b, bA, { v = v > 0.0f ? v : 0.01f * v; })
    __syncthreads();

    // l4: K=128 -> lrelu -> l5 partials in registers -> red
    {
        f32x4 acc[2][2] = {};
        gemm_sw<128>(bA, l4t, w, l16, l4g, acc);
        float bbr[2][4], w5[2][4][3];
#pragma unroll
        for (int mi = 0; mi < 2; ++mi)
#pragma unroll
            for (int rg = 0; rg < 4; ++rg) {
                int ch = 32 * w + 16 * mi + l4g * 4 + rg;
                bbr[mi][rg] = l4b[ch];
#pragma unroll
                for (int cc = 0; cc < 3; ++cc) w5[mi][rg][cc] = l5w[ch * 3 + cc];
            }
#pragma unroll
        for (int ni = 0; ni < 2; ++ni) {
            float p0 = 0.0f, p1 = 0.0f, p2 = 0.0f;
#pragma unroll
            for (int mi = 0; mi < 2; ++mi)
#pragma unroll
                for (int rg = 0; rg < 4; ++rg) {
                    float v = acc[mi][ni][rg] + bbr[mi][rg];
                    v = v > 0.0f ? v : 0.01f * v;
                    p0 += v * w5[mi][rg][0];
                    p1 += v * w5[mi][rg][1];
                    p2 += v * w5[mi][rg][2];
                }
            const int n = 16 * ni + l16, j = w * 4 + l4g;
            red[n][0][j] = p0;
            red[n][1][j] = p1;
            red[n][2][j] = p2;
        }
    }
    __syncthreads();

    if (t < 96) {
        int n = t / 3, cc = t % 3;
        float s = l5b[cc];
#pragma unroll
        for (int j = 0; j < 16; ++j) s += red[n][cc][j];
        out[(size_t)(n0 + n) * 3 + cc] = s;
    }
}

extern "C" void kernel_launch(void* const* d_in, const int* in_sizes, int n_in,
                              void* d_out, int out_size, void* d_ws, size_t ws_size,
                              hipStream_t stream)
{
    const float* x      = (const float*)d_in[0];
    const float* pos    = (const float*)d_in[1];
    const int*   eidx   = (const int*)d_in[2];
    const float* fe_w1  = (const float*)d_in[3];
    const float* fe_b1  = (const float*)d_in[4];
    const float* fe_w2  = (const float*)d_in[5];
    const float* fe_b2  = (const float*)d_in[6];
    const float* finf_w = (const float*)d_in[7];
    const float* finf_b = (const float*)d_in[8];
    const float* fh_w1  = (const float*)d_in[9];
    const float* fh_b1  = (const float*)d_in[10];
    const float* fh_w2  = (const float*)d_in[11];
    const float* fh_b2  = (const float*)d_in[12];
    const float* l1w    = (const float*)d_in[13];
    const float* l1b    = (const float*)d_in[14];
    const float* l2w    = (const float*)d_in[15];
    const float* l2b    = (const float*)d_in[16];
    const float* l3w    = (const float*)d_in[17];
    const float* l3b    = (const float*)d_in[18];
    const float* l4w    = (const float*)d_in[19];
    const float* l4b    = (const float*)d_in[20];
    const float* l5w    = (const float*)d_in[21];
    const float* l5b    = (const float*)d_in[22];
    float* out = (float*)d_out;

    const int n_edges = in_sizes[2] / 2;             // 600000
    const int n_nodes = in_sizes[0] / HID;           // 100000
    const int nsb     = (n_nodes + 255) / 256;       // 391 scan blocks
    const int n_tiles = n_edges / 32;                // 18750
    const int nxb     = (n_nodes * HID) / (256 * 8); // 6250 prep_x blocks
    const int nhb     = (n_edges + 255) / 256;       // 2344 hist blocks

    char* ws = (char*)d_ws;
    const bool use_csr = (ws_size >= 208800000ULL);

    if (use_csr) {
        u16* g     = (u16*)(ws + 0);                 // 153,600,000 B
        u16* xb    = (u16*)(ws + 153600000);         //  25,600,000 B
        u16* m_i   = (u16*)(ws + 179200000);         //  25,600,000 B (bf16)
        int* est_s  = (int*)(ws + 179200000);        //   2,400,000 B (overlay, dead before m_i)
        int* eend_s = (int*)(ws + 181600000);        //   2,400,000 B
        u16* w1t  = (u16*)(ws + 204800000);
        u16* w2t  = (u16*)(ws + 204865536);
        u16* fh1t = (u16*)(ws + 204898304);
        u16* fh2t = (u16*)(ws + 204963840);
        u16* l1t  = (u16*)(ws + 204996608);
        u16* l2t  = (u16*)(ws + 205029376);
        u16* l3t  = (u16*)(ws + 205062144);
        u16* l4t  = (u16*)(ws + 205094912);
        int* cnt  = (int*)(ws + 205127680);          // 400,000 B
        int* offs = (int*)(ws + 205527680);          // 400,016 B (N+1 ints)
        int* cur  = (int*)(ws + 205927696);          // 400,000 B
        float* ev = (float*)(ws + 206327696);        // 2,400,000 B
        int* part = (int*)(ws + 208727696);          // scan partials

        (void)hipMemsetAsync(cnt, 0, (size_t)n_nodes * sizeof(int), stream);
        prep_combo<<<dim3(nxb + 640 + nhb), dim3(256), 0, stream>>>(
            x, xb, fe_w1, fh_w1, fe_w2, fh_w2, l1w, l2w, l3w, l4w,
            w1t, fh1t, w2t, fh2t, l1t, l2t, l3t, l4t, eidx, cnt, n_edges, nxb);

        scan1<<<dim3(nsb), dim3(256), 0, stream>>>(cnt, cnt, part, n_nodes);
        scan2<<<dim3(1), dim3(512), 0, stream>>>(part, nsb);
        scan3<<<dim3(nsb), dim3(256), 0, stream>>>(cnt, part, offs, cur, n_nodes, n_edges);
        reorder_kernel<<<dim3(nhb), dim3(256), 0, stream>>>(
            eidx, eidx + n_edges, cur, est_s, eend_s, n_edges);

        egc_edge_csr<<<dim3(768), dim3(256), 0, stream>>>(
            xb, pos, est_s, eend_s, w1t, fe_w1 + (size_t)256 * HID, fe_b1,
            w2t, fe_b2, finf_w, finf_b, g, ev, n_tiles);

        gather_seq<<<dim3(n_nodes / 4), dim3(256), 0, stream>>>(g, ev, offs, m_i);

        egc_node_mfma<0><<<dim3(n_nodes / 32), dim3(256), 0, stream>>>(
            xb, m_i, fh1t, fh_b1, fh2t, fh_b2, l1t, l1b, l2t, l2b,
            l3t, l3b, l4t, l4b, l5w, l5b, out);
    } else {
        // fallback: round-3 fused atomic path
        float* m_i = (float*)(ws + 0);
        u16* xb    = (u16*)(ws + 51200000);
        u16* w1t   = (u16*)(ws + 76800000);
        u16* w2t   = (u16*)(ws + 76865536);
        u16* fh1t  = (u16*)(ws + 76898304);
        u16* fh2t  = (u16*)(ws + 76963840);
        u16* l1t   = (u16*)(ws + 76996608);
        u16* l2t   = (u16*)(ws + 77029376);
        u16* l3t   = (u16*)(ws + 77062144);
        u16* l4t   = (u16*)(ws + 77094912);

        (void)hipMemsetAsync(m_i, 0, (size_t)n_nodes * HID * sizeof(float), stream);
        prep_combo<<<dim3(nxb + 640), dim3(256), 0, stream>>>(
            x, xb, fe_w1, fh_w1, fe_w2, fh_w2, l1w, l2w, l3w, l4w,
            w1t, fh1t, w2t, fh2t, l1t, l2t, l3t, l4t, eidx, (int*)d_ws, 0, nxb);

        egc_edge_mfma<<<dim3(n_edges / 32), dim3(256), 0, stream>>>(
            xb, pos, eidx, eidx + n_edges, w1t, fe_w1 + (size_t)256 * HID, fe_b1,
            w2t, fe_b2, finf_w, finf_b, m_i);

        egc_node_mfma<1><<<dim3(n_nodes / 32), dim3(256), 0, stream>>>(
            xb, m_i, fh1t, fh_b1, fh2t, fh_b2, l1t, l1b, l2t, l2b,
            l3t, l3b, l4t, l4b, l5w, l5b, out);
    }
}

// Round 15
// 333.763 us; speedup vs baseline: 1.0532x; 1.0532x over previous
//
#include <hip/hip_runtime.h>
#include <hip/hip_bf16.h>
#include <math.h>

#define HID 128

typedef unsigned short u16;
typedef __attribute__((ext_vector_type(8))) short bfrag;      // 8 bf16 (4 VGPRs)
typedef __attribute__((ext_vector_type(4))) float f32x4;      // MFMA C/D
typedef __attribute__((ext_vector_type(8))) unsigned short u16x8;
typedef __attribute__((ext_vector_type(4))) unsigned short u16x4;

// saturates correctly without clamp: v>>0 -> e=inf -> rcp=0 -> 1; v<<0 -> e~0 -> -1
__device__ __forceinline__ float fast_tanh(float v) {
    float e = __expf(2.0f * v);
    float r = __builtin_amdgcn_rcpf(e + 1.0f);
    return 1.0f - 2.0f * r;
}

// fp32 -> bf16 via HW convert (compiler pairs these into v_cvt_pk_bf16_f32)
__device__ __forceinline__ u16 f2b(float f) {
    __hip_bfloat16 h = __float2bfloat16(f);
    return *(u16*)&h;
}
__device__ __forceinline__ float bits2f(unsigned u) {
    union { unsigned u; float f; } v; v.u = u; return v.f;
}
__device__ __forceinline__ float b2f(u16 b) {
    return bits2f(((unsigned)b) << 16);
}

// ---------------- merged prep: x->bf16 | weights->k-major bf16 | hist ----------------
__global__ void __launch_bounds__(256) prep_combo(
    const float* __restrict__ x, u16* __restrict__ xb,
    const float* __restrict__ w1, const float* __restrict__ fh1,
    const float* __restrict__ w2, const float* __restrict__ fh2,
    const float* __restrict__ l1, const float* __restrict__ l2,
    const float* __restrict__ l3, const float* __restrict__ l4,
    u16* __restrict__ w1t, u16* __restrict__ fh1t,
    u16* __restrict__ w2t, u16* __restrict__ fh2t,
    u16* __restrict__ l1t, u16* __restrict__ l2t,
    u16* __restrict__ l3t, u16* __restrict__ l4t,
    const int* __restrict__ est, int* __restrict__ cnt, int E, int nxb)
{
    int b = blockIdx.x, t = threadIdx.x;
    if (b < nxb) {
        int i = b * 256 + t;
        const float4 v0 = *(const float4*)(x + (size_t)i * 8);
        const float4 v1 = *(const float4*)(x + (size_t)i * 8 + 4);
        u16x8 o = { f2b(v0.x), f2b(v0.y), f2b(v0.z), f2b(v0.w),
                    f2b(v1.x), f2b(v1.y), f2b(v1.z), f2b(v1.w) };
        *(u16x8*)(xb + (size_t)i * 8) = o;
        return;
    }
    b -= nxb;
    if (b < 640) {
        const float* src; u16* dst; int K;
        if (b < 256) {
            K = 256;
            if (b < 128) { src = w1;  dst = w1t; }
            else         { src = fh1; dst = fh1t; b -= 128; }
        } else {
            K = 128;
            int s = (b - 256) >> 6; b = (b - 256) & 63;
            switch (s) {
                case 0:  src = w2;  dst = w2t;  break;
                case 1:  src = fh2; dst = fh2t; break;
                case 2:  src = l1;  dst = l1t;  break;
                case 3:  src = l2;  dst = l2t;  break;
                case 4:  src = l3;  dst = l3t;  break;
                default: src = l4;  dst = l4t;  break;
            }
        }
        int idx = b * 256 + t;
        int k = idx >> 7, n = idx & 127;
        dst[(size_t)n * K + k] = f2b(src[(size_t)k * 128 + n]);
        return;
    }
    b -= 640;
    int e = b * 256 + t;
    if (e < E) atomicAdd(&cnt[est[e]], 1);
}

// ---------------- CSR build: scan / reorder(sorted edge arrays) ----------------
__global__ void __launch_bounds__(256) scan1(const int* __restrict__ cnt,
                                             int* __restrict__ scanout,
                                             int* __restrict__ partial, int N) {
    __shared__ int s[256];
    int t = threadIdx.x, b = blockIdx.x, i = b * 256 + t;
    int v = (i < N) ? cnt[i] : 0;
    s[t] = v; __syncthreads();
#pragma unroll
    for (int d = 1; d < 256; d <<= 1) {
        int add = (t >= d) ? s[t - d] : 0;
        __syncthreads();
        s[t] += add;
        __syncthreads();
    }
    if (i < N) scanout[i] = s[t] - v;
    if (t == 255) partial[b] = s[255];
}

__global__ void __launch_bounds__(512) scan2(int* __restrict__ partial, int NB) {
    __shared__ int s[512];
    int t = threadIdx.x;
    int v = (t < NB) ? partial[t] : 0;
    s[t] = v; __syncthreads();
#pragma unroll
    for (int d = 1; d < 512; d <<= 1) {
        int add = (t >= d) ? s[t - d] : 0;
        __syncthreads();
        s[t] += add;
        __syncthreads();
    }
    if (t < NB) partial[t] = s[t] - v;
}

__global__ void __launch_bounds__(256) scan3(const int* __restrict__ scanout,
                                             const int* __restrict__ partial,
                                             int* __restrict__ offs,
                                             int* __restrict__ cur, int N, int E) {
    int t = threadIdx.x, b = blockIdx.x, i = b * 256 + t;
    if (i < N) { int o = scanout[i] + partial[b]; offs[i] = o; cur[i] = o; }
    if (i == 0) offs[N] = E;
}

__global__ void __launch_bounds__(256) reorder_kernel(const int* __restrict__ est,
                                                      const int* __restrict__ eend,
                                                      int* __restrict__ cur,
                                                      int* __restrict__ est_s,
                                                      int* __restrict__ eend_s, int E) {
    int e = blockIdx.x * 256 + threadIdx.x;
    if (e < E) {
        int s = est[e];
        int p = atomicAdd(&cur[s], 1);
        est_s[p]  = s;
        eend_s[p] = eend[e];
    }
}

// ---------------- GEMM helpers ----------------
template<int KD>
__device__ __forceinline__ void gemm_k(const u16* sbuf, const u16* __restrict__ wt,
                                       int w, int l16, int l4g, f32x4 (&acc)[2][2]) {
    const int RS = KD * 2;
#pragma unroll
    for (int k0 = 0; k0 < KD; k0 += 32) {
        const int kb = k0 * 2 + l4g * 16;
        bfrag a0 = *(const bfrag*)((const char*)sbuf +
                    (unsigned)((l16 * RS + kb) ^ ((l16 & 7) << 4)));
        bfrag a1 = *(const bfrag*)((const char*)sbuf +
                    (unsigned)(((16 + l16) * RS + kb) ^ ((l16 & 7) << 4)));
        bfrag b0 = *(const bfrag*)((const char*)wt + (size_t)(32 * w + l16) * RS + kb);
        bfrag b1 = *(const bfrag*)((const char*)wt + (size_t)(32 * w + 16 + l16) * RS + kb);
        acc[0][0] = __builtin_amdgcn_mfma_f32_16x16x32_bf16(a0, b0, acc[0][0], 0, 0, 0);
        acc[0][1] = __builtin_amdgcn_mfma_f32_16x16x32_bf16(a0, b1, acc[0][1], 0, 0, 0);
        acc[1][0] = __builtin_amdgcn_mfma_f32_16x16x32_bf16(a1, b0, acc[1][0], 0, 0, 0);
        acc[1][1] = __builtin_amdgcn_mfma_f32_16x16x32_bf16(a1, b1, acc[1][1], 0, 0, 0);
    }
}

// Swapped orientation: D[row=out-ch (mi,rg)][col=row-in-tile (ni,l16)]
template<int KD>
__device__ __forceinline__ void gemm_sw(const u16* act, const u16* __restrict__ wt,
                                        int w, int l16, int l4g, f32x4 (&acc)[2][2]) {
    const int RS = KD * 2;
#pragma unroll
    for (int k0 = 0; k0 < KD; k0 += 32) {
        const int kb = k0 * 2 + l4g * 16;
        bfrag wa0 = *(const bfrag*)((const char*)wt + (size_t)(32 * w + l16) * RS + kb);
        bfrag wa1 = *(const bfrag*)((const char*)wt + (size_t)(32 * w + 16 + l16) * RS + kb);
        bfrag be0 = *(const bfrag*)((const char*)act +
                    (unsigned)((l16 * RS + kb) ^ ((l16 & 7) << 4)));
        bfrag be1 = *(const bfrag*)((const char*)act +
                    (unsigned)(((16 + l16) * RS + kb) ^ ((l16 & 7) << 4)));
        acc[0][0] = __builtin_amdgcn_mfma_f32_16x16x32_bf16(wa0, be0, acc[0][0], 0, 0, 0);
        acc[0][1] = __builtin_amdgcn_mfma_f32_16x16x32_bf16(wa0, be1, acc[0][1], 0, 0, 0);
        acc[1][0] = __builtin_amdgcn_mfma_f32_16x16x32_bf16(wa1, be0, acc[1][0], 0, 0, 0);
        acc[1][1] = __builtin_amdgcn_mfma_f32_16x16x32_bf16(wa1, be1, acc[1][1], 0, 0, 0);
    }
}

// ---------------- edge kernel: persistent, single-barrier pipeline (round 13) ----------------
// Phase k (parity p): B1 -> reduce ev(T_{k-2}, red[p^1]) -> issue loads(T_{k+1})
//   -> GEMM1(T_k: a_sh[p] -> m1[p]) -> GEMM2(T_{k-1}: m1[p^1] -> g, red[p])
//   -> commit(T_{k+1} -> a_sh[p^1]).
// __launch_bounds__(256,2): compile budget; (256,3) spills weights (round 7).
// Residency is 2 blocks/CU regardless of source-level VGPR diets (round 14:
// allocator spends the budget; 768-grid = 1.5-round tail) -> grid MUST be 512.
__global__ void __launch_bounds__(256, 2)
egc_edge_csr(const u16* __restrict__ xb, const float* __restrict__ pos,
             const int* __restrict__ est_s, const int* __restrict__ eend_s,
             const u16* __restrict__ w1t, const float* __restrict__ w1last,
             const float* __restrict__ b1, const u16* __restrict__ w2t,
             const float* __restrict__ b2, const float* __restrict__ fw,
             const float* __restrict__ fb, u16* __restrict__ g,
             float* __restrict__ ev, int n_tiles)
{
    __shared__ __attribute__((aligned(16))) u16 a_sh[2][32 * 256];  // 32 KB dbuf, swz
    __shared__ __attribute__((aligned(16))) u16 m1_sh[2][32 * 128]; // 16 KB dbuf, swz
    __shared__ float red[2][32][17];                                // gate partials dbuf
    __shared__ float dist_l[2][32];

    const int t = threadIdx.x, lane = t & 63, w = t >> 6;
    const int l16 = lane & 15, l4g = lane >> 4;
    const unsigned swz = (unsigned)((l16 & 7) << 4);

    bfrag wa10[8], wa11[8], w2f0[4], w2f1[4];
#pragma unroll
    for (int i = 0; i < 8; ++i) {
        int kb = i * 64 + l4g * 16;
        wa10[i] = *(const bfrag*)((const char*)w1t + (size_t)(32 * w + l16) * 512 + kb);
        wa11[i] = *(const bfrag*)((const char*)w1t + (size_t)(32 * w + 16 + l16) * 512 + kb);
    }
#pragma unroll
    for (int i = 0; i < 4; ++i) {
        int kb = i * 64 + l4g * 16;
        w2f0[i] = *(const bfrag*)((const char*)w2t + (size_t)(32 * w + l16) * 256 + kb);
        w2f1[i] = *(const bfrag*)((const char*)w2t + (size_t)(32 * w + 16 + l16) * 256 + kb);
    }
    float w1l_r[2][4], b1_r[2][4], b2_r[2][4], fw_r[2][4];
#pragma unroll
    for (int mi = 0; mi < 2; ++mi)
#pragma unroll
        for (int rg = 0; rg < 4; ++rg) {
            int n = 32 * w + 16 * mi + l4g * 4 + rg;
            w1l_r[mi][rg] = w1last[n];
            b1_r[mi][rg]  = b1[n];
            b2_r[mi][rg]  = b2[n];
            fw_r[mi][rg]  = fw[n];
        }
    const float fbv = fb[0];

    float4 sv0, sv1, sv2, sv3;
    float pax = 0, pay = 0, paz = 0, pbx = 0, pby = 0, pbz = 0;

#define EDGE_ISSUE(TILE) do {                                                  \
        int e0_ = (TILE) * 32;                                                 \
        { int f_ = t;       int e_ = f_ >> 5, q_ = f_ & 31; int ge_ = e0_ + e_;\
          int nd_ = (q_ < 16) ? est_s[ge_] : eend_s[ge_];                      \
          sv0 = *(const float4*)(xb + (size_t)nd_ * 128 + (q_ & 15) * 8); }    \
        { int f_ = t + 256; int e_ = f_ >> 5, q_ = f_ & 31; int ge_ = e0_ + e_;\
          int nd_ = (q_ < 16) ? est_s[ge_] : eend_s[ge_];                      \
          sv1 = *(const float4*)(xb + (size_t)nd_ * 128 + (q_ & 15) * 8); }    \
        { int f_ = t + 512; int e_ = f_ >> 5, q_ = f_ & 31; int ge_ = e0_ + e_;\
          int nd_ = (q_ < 16) ? est_s[ge_] : eend_s[ge_];                      \
          sv2 = *(const float4*)(xb + (size_t)nd_ * 128 + (q_ & 15) * 8); }    \
        { int f_ = t + 768; int e_ = f_ >> 5, q_ = f_ & 31; int ge_ = e0_ + e_;\
          int nd_ = (q_ < 16) ? est_s[ge_] : eend_s[ge_];                      \
          sv3 = *(const float4*)(xb + (size_t)nd_ * 128 + (q_ & 15) * 8); }    \
        if (t < 32) {                                                          \
            int ge_ = e0_ + t;                                                 \
            int a_ = est_s[ge_], b_ = eend_s[ge_];                             \
            pax = pos[a_ * 3]; pay = pos[a_ * 3 + 1]; paz = pos[a_ * 3 + 2];   \
            pbx = pos[b_ * 3]; pby = pos[b_ * 3 + 1]; pbz = pos[b_ * 3 + 2];   \
        }                                                                      \
    } while (0)

#define EDGE_COMMIT(BUF) do {                                                  \
        { int f_ = t;       int e_ = f_ >> 5, q_ = f_ & 31;                    \
          unsigned by_ = (unsigned)(e_ * 512 + q_ * 16) ^ (unsigned)((e_ & 7) << 4); \
          *(float4*)((char*)a_sh[BUF] + by_) = sv0; }                          \
        { int f_ = t + 256; int e_ = f_ >> 5, q_ = f_ & 31;                    \
          unsigned by_ = (unsigned)(e_ * 512 + q_ * 16) ^ (unsigned)((e_ & 7) << 4); \
          *(float4*)((char*)a_sh[BUF] + by_) = sv1; }                          \
        { int f_ = t + 512; int e_ = f_ >> 5, q_ = f_ & 31;                    \
          unsigned by_ = (unsigned)(e_ * 512 + q_ * 16) ^ (unsigned)((e_ & 7) << 4); \
          *(float4*)((char*)a_sh[BUF] + by_) = sv2; }                          \
        { int f_ = t + 768; int e_ = f_ >> 5, q_ = f_ & 31;                    \
          unsigned by_ = (unsigned)(e_ * 512 + q_ * 16) ^ (unsigned)((e_ & 7) << 4); \
          *(float4*)((char*)a_sh[BUF] + by_) = sv3; }                          \
        if (t < 32) {                                                          \
            float dx_ = pax - pbx, dy_ = pay - pby, dz_ = paz - pbz;           \
            dx_ *= dx_; dy_ *= dy_; dz_ *= dz_;                                \
            dist_l[BUF][t] = sqrtf(dx_ * dx_ + dy_ * dy_ + dz_ * dz_);         \
        }                                                                      \
    } while (0)

    auto do_gemm1 = [&](int p) {
        f32x4 acc[2][2] = {};
#pragma unroll
        for (int i = 0; i < 8; ++i) {
            int kb = i * 64 + l4g * 16;
            bfrag be0 = *(const bfrag*)((const char*)a_sh[p] +
                        ((unsigned)(l16 * 512 + kb) ^ swz));
            bfrag be1 = *(const bfrag*)((const char*)a_sh[p] +
                        ((unsigned)((16 + l16) * 512 + kb) ^ swz));
            acc[0][0] = __builtin_amdgcn_mfma_f32_16x16x32_bf16(wa10[i], be0, acc[0][0], 0, 0, 0);
            acc[0][1] = __builtin_amdgcn_mfma_f32_16x16x32_bf16(wa10[i], be1, acc[0][1], 0, 0, 0);
            acc[1][0] = __builtin_amdgcn_mfma_f32_16x16x32_bf16(wa11[i], be0, acc[1][0], 0, 0, 0);
            acc[1][1] = __builtin_amdgcn_mfma_f32_16x16x32_bf16(wa11[i], be1, acc[1][1], 0, 0, 0);
        }
        float de0 = dist_l[p][l16];
        float de1 = dist_l[p][16 + l16];
#pragma unroll
        for (int mi = 0; mi < 2; ++mi)
#pragma unroll
            for (int ni = 0; ni < 2; ++ni) {
                float de = ni ? de1 : de0;
                u16x4 pk;
#pragma unroll
                for (int rg = 0; rg < 4; ++rg) {
                    float v = fast_tanh(acc[mi][ni][rg] + de * w1l_r[mi][rg] + b1_r[mi][rg]);
                    pk[rg] = f2b(v);
                }
                unsigned byte = ((unsigned)((16 * ni + l16) * 256 +
                                 (32 * w + 16 * mi + l4g * 4) * 2)) ^ swz;
                *(u16x4*)((char*)m1_sh[p] + byte) = pk;
            }
    };

    auto do_gemm2 = [&](int e0, int rp, int mp) {
        f32x4 acc[2][2] = {};
#pragma unroll
        for (int i = 0; i < 4; ++i) {
            int kb = i * 64 + l4g * 16;
            bfrag me0 = *(const bfrag*)((const char*)m1_sh[mp] +
                        ((unsigned)(l16 * 256 + kb) ^ swz));
            bfrag me1 = *(const bfrag*)((const char*)m1_sh[mp] +
                        ((unsigned)((16 + l16) * 256 + kb) ^ swz));
            acc[0][0] = __builtin_amdgcn_mfma_f32_16x16x32_bf16(w2f0[i], me0, acc[0][0], 0, 0, 0);
            acc[0][1] = __builtin_amdgcn_mfma_f32_16x16x32_bf16(w2f0[i], me1, acc[0][1], 0, 0, 0);
            acc[1][0] = __builtin_amdgcn_mfma_f32_16x16x32_bf16(w2f1[i], me0, acc[1][0], 0, 0, 0);
            acc[1][1] = __builtin_amdgcn_mfma_f32_16x16x32_bf16(w2f1[i], me1, acc[1][1], 0, 0, 0);
        }
        float part0 = 0.0f, part1 = 0.0f;
#pragma unroll
        for (int mi = 0; mi < 2; ++mi)
#pragma unroll
            for (int ni = 0; ni < 2; ++ni) {
                u16x4 pk;
                float ps = 0.0f;
#pragma unroll
                for (int rg = 0; rg < 4; ++rg) {
                    float v = fast_tanh(acc[mi][ni][rg] + b2_r[mi][rg]);
                    ps += v * fw_r[mi][rg];
                    pk[rg] = f2b(v);
                }
                if (ni) part1 += ps; else part0 += ps;
                int dstrow = e0 + 16 * ni + l16;        // CSR position = sequential
                *(u16x4*)(g + (size_t)dstrow * 128 + (32 * w + 16 * mi + l4g * 4)) = pk;
            }
        red[rp][l16][w * 4 + l4g]      = part0;
        red[rp][16 + l16][w * 4 + l4g] = part1;
    };

    auto do_reduce = [&](int e0, int rp) {
        if (t < 32) {
            float s = 0.0f;
#pragma unroll
            for (int j = 0; j < 16; ++j) s += red[rp][t][j];
            ev[e0 + t] = fast_tanh(s + fbv);
        }
    };

    int t1 = blockIdx.x;            // GEMM1 tile this phase
    int t2 = -1, tr = -1;           // GEMM2 tile / reduce tile
    int pk = 0;
    EDGE_ISSUE(t1);
    EDGE_COMMIT(0);
    int tnext = t1 + gridDim.x;

    while (true) {
        __syncthreads();                                 // B1 (one per tile)
        if (tr >= 0) do_reduce(tr * 32, pk ^ 1);
        bool have_next = (tnext < n_tiles);
        if (have_next) EDGE_ISSUE(tnext);
        do_gemm1(pk);
        if (t2 >= 0) do_gemm2(t2 * 32, pk, pk ^ 1);
        if (have_next) EDGE_COMMIT(pk ^ 1);
        tr = t2; t2 = t1;
        if (!have_next) break;
        t1 = tnext; tnext += gridDim.x; pk ^= 1;
    }
    // drain: GEMM2 for the last tile (m1 in m1_sh[pk]), plus two final reduces
    __syncthreads();
    if (tr >= 0) do_reduce(tr * 32, pk);
    do_gemm2(t2 * 32, pk ^ 1, pk);
    __syncthreads();
    do_reduce(t2 * 32, pk ^ 1);
#undef EDGE_ISSUE
#undef EDGE_COMMIT
}

// ---------------- gather: half-wave per edge parity, 4 edges in flight ----------------
__global__ void __launch_bounds__(256, 8)
gather_seq(const u16* __restrict__ g, const float* __restrict__ ev,
           const int* __restrict__ offs, u16* __restrict__ m_i)
{
    const int lane = threadIdx.x & 63;
    const int half = lane >> 5;
    const int l32  = lane & 31;
    const int n = blockIdx.x * 4 + (threadIdx.x >> 6);
    const int beg = offs[n], end = offs[n + 1];
    float a0 = 0.0f, a1 = 0.0f, a2 = 0.0f, a3 = 0.0f;
    float b0 = 0.0f, b1 = 0.0f, b2 = 0.0f, b3 = 0.0f;
    int e = beg + half;
    for (; e + 3 < end; e += 4) {
        uint2 v0 = *(const uint2*)(g + (size_t)e * 128 + l32 * 4);
        uint2 v1 = *(const uint2*)(g + (size_t)(e + 2) * 128 + l32 * 4);
        float e0 = ev[e], e1 = ev[e + 2];
        a0 += e0 * bits2f(v0.x << 16);
        a1 += e0 * bits2f(v0.x & 0xFFFF0000u);
        a2 += e0 * bits2f(v0.y << 16);
        a3 += e0 * bits2f(v0.y & 0xFFFF0000u);
        b0 += e1 * bits2f(v1.x << 16);
        b1 += e1 * bits2f(v1.x & 0xFFFF0000u);
        b2 += e1 * bits2f(v1.y << 16);
        b3 += e1 * bits2f(v1.y & 0xFFFF0000u);
    }
    for (; e < end; e += 2) {
        uint2 v0 = *(const uint2*)(g + (size_t)e * 128 + l32 * 4);
        float e0 = ev[e];
        a0 += e0 * bits2f(v0.x << 16);
        a1 += e0 * bits2f(v0.x & 0xFFFF0000u);
        a2 += e0 * bits2f(v0.y << 16);
        a3 += e0 * bits2f(v0.y & 0xFFFF0000u);
    }
    a0 += b0; a1 += b1; a2 += b2; a3 += b3;
    a0 += __shfl_xor(a0, 32);
    a1 += __shfl_xor(a1, 32);
    a2 += __shfl_xor(a2, 32);
    a3 += __shfl_xor(a3, 32);
    if (half == 0) {
        uint2 o;
        o.x = (unsigned)f2b(a0) | ((unsigned)f2b(a1) << 16);
        o.y = (unsigned)f2b(a2) | ((unsigned)f2b(a3) << 16);
        *(uint2*)(m_i + (size_t)n * 128 + l32 * 4) = o;
    }
}

// ---------------- edge kernel, fallback atomic path (round-3, proven) ----------------
__global__ void __launch_bounds__(256, 3)
egc_edge_mfma(const u16* __restrict__ xb, const float* __restrict__ pos,
              const int* __restrict__ est, const int* __restrict__ eend,
              const u16* __restrict__ w1t, const float* __restrict__ w1last,
              const float* __restrict__ b1, const u16* __restrict__ w2t,
              const float* __restrict__ b2, const float* __restrict__ fw,
              const float* __restrict__ fb, float* __restrict__ m_i)
{
    __shared__ __attribute__((aligned(16))) u16 a_sh[32 * 256];
    __shared__ __attribute__((aligned(16))) u16 m1_sh[32 * 128];
    __shared__ float m2_sh[32][132];
    __shared__ float dist_l[32];
    __shared__ float ev_l[32];
    __shared__ int   st_l[32];

    const int t = threadIdx.x;
    const int e0 = blockIdx.x * 32;
    const int lane = t & 63;
    const int w = t >> 6;
    const int l16 = lane & 15, l4g = lane >> 4;

#pragma unroll
    for (int i = 0; i < 4; ++i) {
        int f = t + 256 * i;
        int e = f >> 5, q = f & 31;
        int ge = e0 + e;
        int node = (q < 16) ? est[ge] : eend[ge];
        float4 v = *(const float4*)(xb + (size_t)node * 128 + (q & 15) * 8);
        unsigned byte = (unsigned)(e * 512 + q * 16) ^ (unsigned)((e & 7) << 4);
        *(float4*)((char*)a_sh + byte) = v;
    }
    if (t < 32) {
        int ge = e0 + t;
        int a = est[ge], b = eend[ge];
        st_l[t] = a;
        float dx = pos[a * 3 + 0] - pos[b * 3 + 0];
        float dy = pos[a * 3 + 1] - pos[b * 3 + 1];
        float dz = pos[a * 3 + 2] - pos[b * 3 + 2];
        dx *= dx; dy *= dy; dz *= dz;
        dist_l[t] = sqrtf(dx * dx + dy * dy + dz * dz);
    }
    __syncthreads();

    {
        f32x4 acc[2][2] = {};
        gemm_k<256>(a_sh, w1t, w, l16, l4g, acc);
#pragma unroll
        for (int mi = 0; mi < 2; ++mi)
#pragma unroll
            for (int ni = 0; ni < 2; ++ni) {
                const int col = 32 * w + 16 * ni + l16;
                const float wl = w1last[col], bb = b1[col];
#pragma unroll
                for (int rg = 0; rg < 4; ++rg) {
                    const int row = 16 * mi + l4g * 4 + rg;
                    float v = fast_tanh(acc[mi][ni][rg] + dist_l[row] * wl + bb);
                    unsigned byte = (unsigned)((row * 256 + col * 2) ^ ((row & 7) << 4));
                    *(u16*)((char*)m1_sh + byte) = f2b(v);
                }
            }
    }
    __syncthreads();

    {
        f32x4 acc[2][2] = {};
        gemm_k<128>(m1_sh, w2t, w, l16, l4g, acc);
#pragma unroll
        for (int mi = 0; mi < 2; ++mi)
#pragma unroll
            for (int ni = 0; ni < 2; ++ni) {
                const int col = 32 * w + 16 * ni + l16;
                const float bb = b2[col];
#pragma unroll
                for (int rg = 0; rg < 4; ++rg) {
                    const int row = 16 * mi + l4g * 4 + rg;
                    m2_sh[row][col] = fast_tanh(acc[mi][ni][rg] + bb);
                }
            }
    }
    __syncthreads();

    if (t < 128) {
        int e = t >> 2, p = t & 3;
        float s = 0.0f;
#pragma unroll
        for (int k = 0; k < 32; ++k) s += m2_sh[e][p * 32 + k] * fw[p * 32 + k];
        s += __shfl_xor(s, 1);
        s += __shfl_xor(s, 2);
        if (p == 0) ev_l[e] = fast_tanh(s + fb[0]);
    }
    __syncthreads();

    {
        int e = t >> 3, l8 = t & 7;
        float ev = ev_l[e];
        size_t base = (size_t)st_l[e] * HID + l8;
#pragma unroll
        for (int i = 0; i < 16; ++i)
            unsafeAtomicAdd(m_i + base + 8 * i, ev * m2_sh[e][l8 + 8 * i]);
    }
}

// ---------------- node kernel: swapped-operand layers, register l5 head ----------------
#define NODE_LAYER_SW(SRC, KD, WT, BIAS, DST, ACT)                             \
    {                                                                          \
        f32x4 acc[2][2] = {};                                                  \
        gemm_sw<KD>(SRC, WT, w, l16, l4g, acc);                                \
        float bbr[2][4];                                                       \
        _Pragma("unroll")                                                      \
        for (int mi = 0; mi < 2; ++mi)                                         \
            _Pragma("unroll")                                                  \
            for (int rg = 0; rg < 4; ++rg)                                     \
                bbr[mi][rg] = (BIAS)[32 * w + 16 * mi + l4g * 4 + rg];         \
        _Pragma("unroll")                                                      \
        for (int mi = 0; mi < 2; ++mi)                                         \
            _Pragma("unroll")                                                  \
            for (int ni = 0; ni < 2; ++ni) {                                   \
                const int node = 16 * ni + l16;                                \
                const int ch = 32 * w + 16 * mi + l4g * 4;                     \
                u16x4 pk;                                                      \
                _Pragma("unroll")                                              \
                for (int rg = 0; rg < 4; ++rg) {                               \
                    float v = acc[mi][ni][rg] + bbr[mi][rg];                   \
                    ACT;                                                       \
                    pk[rg] = f2b(v);                                           \
                }                                                              \
                unsigned byte = ((unsigned)(node * 256 + ch * 2)) ^ swz;       \
                *(u16x4*)((char*)(DST) + byte) = pk;                           \
            }                                                                  \
    }

// MODE 0: CSR path — m_i is bf16. MODE 1: fallback — m_i is fp32.
// LDS 38.9 KB, 4 blocks/CU (round 12). Residual read from a_sh's x half
// (intact when fh2 runs) — no global xf traffic (round 14, validated).
template<int MODE>
__global__ void __launch_bounds__(256, 4)
egc_node_mfma(const u16* __restrict__ xb,
              const void* __restrict__ m_i,
              const u16* __restrict__ fh1t, const float* __restrict__ hb1,
              const u16* __restrict__ fh2t, const float* __restrict__ hb2,
              const u16* __restrict__ l1t, const float* __restrict__ l1b,
              const u16* __restrict__ l2t, const float* __restrict__ l2b,
              const u16* __restrict__ l3t, const float* __restrict__ l3b,
              const u16* __restrict__ l4t, const float* __restrict__ l4b,
              const float* __restrict__ l5w, const float* __restrict__ l5b,
              float* __restrict__ out)
{
    __shared__ __attribute__((aligned(16))) u16 a_sh[32 * 256];   // 16 KB
    __shared__ __attribute__((aligned(16))) u16 bA[32 * 128];     // 8 KB
    __shared__ __attribute__((aligned(16))) u16 bB[32 * 128];     // 8 KB
    __shared__ float red[32][3][17];                              // 6.4 KB l5 partials

    const int t = threadIdx.x;
    const int n0 = blockIdx.x * 32;
    const int lane = t & 63;
    const int w = t >> 6;
    const int l16 = lane & 15, l4g = lane >> 4;
    const unsigned swz = (unsigned)((l16 & 7) << 4);

#pragma unroll
    for (int i = 0; i < 2; ++i) {
        int f = t + 256 * i;
        int n = f >> 4, q = f & 15;
        float4 v = *(const float4*)(xb + (size_t)(n0 + n) * 128 + q * 8);
        unsigned byte = (unsigned)((n * 512 + q * 16) ^ ((n & 7) << 4));
        *(float4*)((char*)a_sh + byte) = v;
    }
    if (MODE == 0) {
#pragma unroll
        for (int i = 0; i < 2; ++i) {
            int f = t + 256 * i;
            int n = f >> 4, q = f & 15;
            float4 v = *(const float4*)((const u16*)m_i + (size_t)(n0 + n) * 128 + q * 8);
            unsigned byte = (unsigned)((n * 512 + 256 + q * 16) ^ ((n & 7) << 4));
            *(float4*)((char*)a_sh + byte) = v;
        }
    } else {
#pragma unroll
        for (int i = 0; i < 2; ++i) {
            int f = t + 256 * i;
            int n = f >> 4, q = f & 15;
            const float* src = (const float*)m_i + (size_t)(n0 + n) * 128 + q * 8;
            float4 v0 = *(const float4*)(src);
            float4 v1 = *(const float4*)(src + 4);
            u16x8 o = { f2b(v0.x), f2b(v0.y), f2b(v0.z), f2b(v0.w),
                        f2b(v1.x), f2b(v1.y), f2b(v1.z), f2b(v1.w) };
            unsigned byte = (unsigned)((n * 512 + 256 + q * 16) ^ ((n & 7) << 4));
            *(u16x8*)((char*)a_sh + byte) = o;
        }
    }
    __syncthreads();

    NODE_LAYER_SW(a_sh, 256, fh1t, hb1, bA, { v = fast_tanh(v); })
    __syncthreads();

    // fh2: K=128, + residual from a_sh's x half (bf16, swizzled 8 B read) -> bB
    {
        f32x4 acc[2][2] = {};
        gemm_sw<128>(bA, fh2t, w, l16, l4g, acc);
        float bbr[2][4];
#pragma unroll
        for (int mi = 0; mi < 2; ++mi)
#pragma unroll
            for (int rg = 0; rg < 4; ++rg)
                bbr[mi][rg] = hb2[32 * w + 16 * mi + l4g * 4 + rg];
#pragma unroll
        for (int mi = 0; mi < 2; ++mi)
#pragma unroll
            for (int ni = 0; ni < 2; ++ni) {
                const int node = 16 * ni + l16;
                const int ch = 32 * w + 16 * mi + l4g * 4;
                unsigned rb = ((unsigned)(node * 512 + ch * 2)) ^
                              ((unsigned)((node & 7) << 4));
                u16x4 xr = *(const u16x4*)((const char*)a_sh + rb);
                u16x4 pk;
                pk[0] = f2b(acc[mi][ni][0] + bbr[mi][0] + b2f(xr[0]));
                pk[1] = f2b(acc[mi][ni][1] + bbr[mi][1] + b2f(xr[1]));
                pk[2] = f2b(acc[mi][ni][2] + bbr[mi][2] + b2f(xr[2]));
                pk[3] = f2b(acc[mi][ni][3] + bbr[mi][3] + b2f(xr[3]));
                unsigned byte = ((unsigned)(node * 256 + ch * 2)) ^ swz;
                *(u16x4*)((char*)bB + byte) = pk;
            }
    }
    __syncthreads();

    NODE_LAYER_SW(bB, 128, l1t, l1b, bA, { v = v > 0.0f ? v : 0.01f * v; })
    __syncthreads();
    NODE_LAYER_SW(bA, 128, l2t, l2b, bB, { v = v > 0.0f ? v : 0.01f * v; })
    __syncthreads();
    NODE_LAYER_SW(bB, 128, l3t, l3b, bA, { v = v > 0.0f ? v : 0.01f * v; })
    __syncthreads();

    // l4: K=128 -> lrelu -> l5 partials in registers -> red
    {
        f32x4 acc[2][2] = {};
        gemm_sw<128>(bA, l4t, w, l16, l4g, acc);
        float bbr[2][4], w5[2][4][3];
#pragma unroll
        for (int mi = 0; mi < 2; ++mi)
#pragma unroll
            for (int rg = 0; rg < 4; ++rg) {
                int ch = 32 * w + 16 * mi + l4g * 4 + rg;
                bbr[mi][rg] = l4b[ch];
#pragma unroll
                for (int cc = 0; cc < 3; ++cc) w5[mi][rg][cc] = l5w[ch * 3 + cc];
            }
#pragma unroll
        for (int ni = 0; ni < 2; ++ni) {
            float p0 = 0.0f, p1 = 0.0f, p2 = 0.0f;
#pragma unroll
            for (int mi = 0; mi < 2; ++mi)
#pragma unroll
                for (int rg = 0; rg < 4; ++rg) {
                    float v = acc[mi][ni][rg] + bbr[mi][rg];
                    v = v > 0.0f ? v : 0.01f * v;
                    p0 += v * w5[mi][rg][0];
                    p1 += v * w5[mi][rg][1];
                    p2 += v * w5[mi][rg][2];
                }
            const int n = 16 * ni + l16, j = w * 4 + l4g;
            red[n][0][j] = p0;
            red[n][1][j] = p1;
            red[n][2][j] = p2;
        }
    }
    __syncthreads();

    if (t < 96) {
        int n = t / 3, cc = t % 3;
        float s = l5b[cc];
#pragma unroll
        for (int j = 0; j < 16; ++j) s += red[n][cc][j];
        out[(size_t)(n0 + n) * 3 + cc] = s;
    }
}

extern "C" void kernel_launch(void* const* d_in, const int* in_sizes, int n_in,
                              void* d_out, int out_size, void* d_ws, size_t ws_size,
                              hipStream_t stream)
{
    const float* x      = (const float*)d_in[0];
    const float* pos    = (const float*)d_in[1];
    const int*   eidx   = (const int*)d_in[2];
    const float* fe_w1  = (const float*)d_in[3];
    const float* fe_b1  = (const float*)d_in[4];
    const float* fe_w2  = (const float*)d_in[5];
    const float* fe_b2  = (const float*)d_in[6];
    const float* finf_w = (const float*)d_in[7];
    const float* finf_b = (const float*)d_in[8];
    const float* fh_w1  = (const float*)d_in[9];
    const float* fh_b1  = (const float*)d_in[10];
    const float* fh_w2  = (const float*)d_in[11];
    const float* fh_b2  = (const float*)d_in[12];
    const float* l1w    = (const float*)d_in[13];
    const float* l1b    = (const float*)d_in[14];
    const float* l2w    = (const float*)d_in[15];
    const float* l2b    = (const float*)d_in[16];
    const float* l3w    = (const float*)d_in[17];
    const float* l3b    = (const float*)d_in[18];
    const float* l4w    = (const float*)d_in[19];
    const float* l4b    = (const float*)d_in[20];
    const float* l5w    = (const float*)d_in[21];
    const float* l5b    = (const float*)d_in[22];
    float* out = (float*)d_out;

    const int n_edges = in_sizes[2] / 2;             // 600000
    const int n_nodes = in_sizes[0] / HID;           // 100000
    const int nsb     = (n_nodes + 255) / 256;       // 391 scan blocks
    const int n_tiles = n_edges / 32;                // 18750
    const int nxb     = (n_nodes * HID) / (256 * 8); // 6250 prep_x blocks
    const int nhb     = (n_edges + 255) / 256;       // 2344 hist blocks

    char* ws = (char*)d_ws;
    const bool use_csr = (ws_size >= 208800000ULL);

    if (use_csr) {
        u16* g     = (u16*)(ws + 0);                 // 153,600,000 B
        u16* xb    = (u16*)(ws + 153600000);         //  25,600,000 B
        u16* m_i   = (u16*)(ws + 179200000);         //  25,600,000 B (bf16)
        int* est_s  = (int*)(ws + 179200000);        //   2,400,000 B (overlay, dead before m_i)
        int* eend_s = (int*)(ws + 181600000);        //   2,400,000 B
        u16* w1t  = (u16*)(ws + 204800000);
        u16* w2t  = (u16*)(ws + 204865536);
        u16* fh1t = (u16*)(ws + 204898304);
        u16* fh2t = (u16*)(ws + 204963840);
        u16* l1t  = (u16*)(ws + 204996608);
        u16* l2t  = (u16*)(ws + 205029376);
        u16* l3t  = (u16*)(ws + 205062144);
        u16* l4t  = (u16*)(ws + 205094912);
        int* cnt  = (int*)(ws + 205127680);          // 400,000 B
        int* offs = (int*)(ws + 205527680);          // 400,016 B (N+1 ints)
        int* cur  = (int*)(ws + 205927696);          // 400,000 B
        float* ev = (float*)(ws + 206327696);        // 2,400,000 B
        int* part = (int*)(ws + 208727696);          // scan partials

        (void)hipMemsetAsync(cnt, 0, (size_t)n_nodes * sizeof(int), stream);
        prep_combo<<<dim3(nxb + 640 + nhb), dim3(256), 0, stream>>>(
            x, xb, fe_w1, fh_w1, fe_w2, fh_w2, l1w, l2w, l3w, l4w,
            w1t, fh1t, w2t, fh2t, l1t, l2t, l3t, l4t, eidx, cnt, n_edges, nxb);

        scan1<<<dim3(nsb), dim3(256), 0, stream>>>(cnt, cnt, part, n_nodes);
        scan2<<<dim3(1), dim3(512), 0, stream>>>(part, nsb);
        scan3<<<dim3(nsb), dim3(256), 0, stream>>>(cnt, part, offs, cur, n_nodes, n_edges);
        reorder_kernel<<<dim3(nhb), dim3(256), 0, stream>>>(
            eidx, eidx + n_edges, cur, est_s, eend_s, n_edges);

        egc_edge_csr<<<dim3(512), dim3(256), 0, stream>>>(
            xb, pos, est_s, eend_s, w1t, fe_w1 + (size_t)256 * HID, fe_b1,
            w2t, fe_b2, finf_w, finf_b, g, ev, n_tiles);

        gather_seq<<<dim3(n_nodes / 4), dim3(256), 0, stream>>>(g, ev, offs, m_i);

        egc_node_mfma<0><<<dim3(n_nodes / 32), dim3(256), 0, stream>>>(
            xb, m_i, fh1t, fh_b1, fh2t, fh_b2, l1t, l1b, l2t, l2b,
            l3t, l3b, l4t, l4b, l5w, l5b, out);
    } else {
        // fallback: round-3 fused atomic path
        float* m_i = (float*)(ws + 0);
        u16* xb    = (u16*)(ws + 51200000);
        u16* w1t   = (u16*)(ws + 76800000);
        u16* w2t   = (u16*)(ws + 76865536);
        u16* fh1t  = (u16*)(ws + 76898304);
        u16* fh2t  = (u16*)(ws + 76963840);
        u16* l1t   = (u16*)(ws + 76996608);
        u16* l2t   = (u16*)(ws + 77029376);
        u16* l3t   = (u16*)(ws + 77062144);
        u16* l4t   = (u16*)(ws + 77094912);

        (void)hipMemsetAsync(m_i, 0, (size_t)n_nodes * HID * sizeof(float), stream);
        prep_combo<<<dim3(nxb + 640), dim3(256), 0, stream>>>(
            x, xb, fe_w1, fh_w1, fe_w2, fh_w2, l1w, l2w, l3w, l4w,
            w1t, fh1t, w2t, fh2t, l1t, l2t, l3t, l4t, eidx, (int*)d_ws, 0, nxb);

        egc_edge_mfma<<<dim3(n_edges / 32), dim3(256), 0, stream>>>(
            xb, pos, eidx, eidx + n_edges, w1t, fe_w1 + (size_t)256 * HID, fe_b1,
            w2t, fe_b2, finf_w, finf_b, m_i);

        egc_node_mfma<1><<<dim3(n_nodes / 32), dim3(256), 0, stream>>>(
            xb, m_i, fh1t, fh_b1, fh2t, fh_b2, l1t, l1b, l2t, l2b,
            l3t, l3b, l4t, l4b, l5w, l5b, out);
    }
}

// Round 16
// 332.517 us; speedup vs baseline: 1.0571x; 1.0037x over previous
//
#include <hip/hip_runtime.h>
#include <hip/hip_bf16.h>
#include <math.h>

#define HID 128

typedef unsigned short u16;
typedef __attribute__((ext_vector_type(8))) short bfrag;      // 8 bf16 (4 VGPRs)
typedef __attribute__((ext_vector_type(4))) float f32x4;      // MFMA C/D
typedef __attribute__((ext_vector_type(8))) unsigned short u16x8;
typedef __attribute__((ext_vector_type(4))) unsigned short u16x4;

// saturates correctly without clamp: v>>0 -> e=inf -> rcp=0 -> 1; v<<0 -> e~0 -> -1
__device__ __forceinline__ float fast_tanh(float v) {
    float e = __expf(2.0f * v);
    float r = __builtin_amdgcn_rcpf(e + 1.0f);
    return 1.0f - 2.0f * r;
}

// fp32 -> bf16 via HW convert (compiler pairs these into v_cvt_pk_bf16_f32)
__device__ __forceinline__ u16 f2b(float f) {
    __hip_bfloat16 h = __float2bfloat16(f);
    return *(u16*)&h;
}
__device__ __forceinline__ float bits2f(unsigned u) {
    union { unsigned u; float f; } v; v.u = u; return v.f;
}
__device__ __forceinline__ float b2f(u16 b) {
    return bits2f(((unsigned)b) << 16);
}

// ---------------- merged prep: x->bf16 | weights->k-major bf16 | hist ----------------
__global__ void __launch_bounds__(256) prep_combo(
    const float* __restrict__ x, u16* __restrict__ xb,
    const float* __restrict__ w1, const float* __restrict__ fh1,
    const float* __restrict__ w2, const float* __restrict__ fh2,
    const float* __restrict__ l1, const float* __restrict__ l2,
    const float* __restrict__ l3, const float* __restrict__ l4,
    u16* __restrict__ w1t, u16* __restrict__ fh1t,
    u16* __restrict__ w2t, u16* __restrict__ fh2t,
    u16* __restrict__ l1t, u16* __restrict__ l2t,
    u16* __restrict__ l3t, u16* __restrict__ l4t,
    const int* __restrict__ est, int* __restrict__ cnt, int E, int nxb)
{
    int b = blockIdx.x, t = threadIdx.x;
    if (b < nxb) {
        int i = b * 256 + t;
        const float4 v0 = *(const float4*)(x + (size_t)i * 8);
        const float4 v1 = *(const float4*)(x + (size_t)i * 8 + 4);
        u16x8 o = { f2b(v0.x), f2b(v0.y), f2b(v0.z), f2b(v0.w),
                    f2b(v1.x), f2b(v1.y), f2b(v1.z), f2b(v1.w) };
        *(u16x8*)(xb + (size_t)i * 8) = o;
        return;
    }
    b -= nxb;
    if (b < 640) {
        const float* src; u16* dst; int K;
        if (b < 256) {
            K = 256;
            if (b < 128) { src = w1;  dst = w1t; }
            else         { src = fh1; dst = fh1t; b -= 128; }
        } else {
            K = 128;
            int s = (b - 256) >> 6; b = (b - 256) & 63;
            switch (s) {
                case 0:  src = w2;  dst = w2t;  break;
                case 1:  src = fh2; dst = fh2t; break;
                case 2:  src = l1;  dst = l1t;  break;
                case 3:  src = l2;  dst = l2t;  break;
                case 4:  src = l3;  dst = l3t;  break;
                default: src = l4;  dst = l4t;  break;
            }
        }
        int idx = b * 256 + t;
        int k = idx >> 7, n = idx & 127;
        dst[(size_t)n * K + k] = f2b(src[(size_t)k * 128 + n]);
        return;
    }
    b -= 640;
    int e = b * 256 + t;
    if (e < E) atomicAdd(&cnt[est[e]], 1);
}

// ---------------- CSR build: scan1 / scan3(self-base) / reorder ----------------
__global__ void __launch_bounds__(256) scan1(const int* __restrict__ cnt,
                                             int* __restrict__ scanout,
                                             int* __restrict__ partial, int N) {
    __shared__ int s[256];
    int t = threadIdx.x, b = blockIdx.x, i = b * 256 + t;
    int v = (i < N) ? cnt[i] : 0;
    s[t] = v; __syncthreads();
#pragma unroll
    for (int d = 1; d < 256; d <<= 1) {
        int add = (t >= d) ? s[t - d] : 0;
        __syncthreads();
        s[t] += add;
        __syncthreads();
    }
    if (i < N) scanout[i] = s[t] - v;
    if (t == 255) partial[b] = s[255];
}

// computes its own base = sum(partial[0..b)) — replaces the old scan2+scan3 pair
__global__ void __launch_bounds__(256) scan3(const int* __restrict__ scanout,
                                             const int* __restrict__ partial,
                                             int* __restrict__ offs,
                                             int* __restrict__ cur, int N, int E) {
    __shared__ int sred[256];
    int t = threadIdx.x, b = blockIdx.x, i = b * 256 + t;
    int s = 0;
    for (int j = t; j < b; j += 256) s += partial[j];
    sred[t] = s;
    __syncthreads();
#pragma unroll
    for (int d = 128; d > 0; d >>= 1) {
        if (t < d) sred[t] += sred[t + d];
        __syncthreads();
    }
    int base = sred[0];
    if (i < N) { int o = scanout[i] + base; offs[i] = o; cur[i] = o; }
    if (b == 0 && t == 0) offs[N] = E;
}

__global__ void __launch_bounds__(256) reorder_kernel(const int* __restrict__ est,
                                                      const int* __restrict__ eend,
                                                      int* __restrict__ cur,
                                                      int* __restrict__ est_s,
                                                      int* __restrict__ eend_s, int E) {
    int e = blockIdx.x * 256 + threadIdx.x;
    if (e < E) {
        int s = est[e];
        int p = atomicAdd(&cur[s], 1);
        est_s[p]  = s;
        eend_s[p] = eend[e];
    }
}

// ---------------- GEMM helpers ----------------
template<int KD>
__device__ __forceinline__ void gemm_k(const u16* sbuf, const u16* __restrict__ wt,
                                       int w, int l16, int l4g, f32x4 (&acc)[2][2]) {
    const int RS = KD * 2;
#pragma unroll
    for (int k0 = 0; k0 < KD; k0 += 32) {
        const int kb = k0 * 2 + l4g * 16;
        bfrag a0 = *(const bfrag*)((const char*)sbuf +
                    (unsigned)((l16 * RS + kb) ^ ((l16 & 7) << 4)));
        bfrag a1 = *(const bfrag*)((const char*)sbuf +
                    (unsigned)(((16 + l16) * RS + kb) ^ ((l16 & 7) << 4)));
        bfrag b0 = *(const bfrag*)((const char*)wt + (size_t)(32 * w + l16) * RS + kb);
        bfrag b1 = *(const bfrag*)((const char*)wt + (size_t)(32 * w + 16 + l16) * RS + kb);
        acc[0][0] = __builtin_amdgcn_mfma_f32_16x16x32_bf16(a0, b0, acc[0][0], 0, 0, 0);
        acc[0][1] = __builtin_amdgcn_mfma_f32_16x16x32_bf16(a0, b1, acc[0][1], 0, 0, 0);
        acc[1][0] = __builtin_amdgcn_mfma_f32_16x16x32_bf16(a1, b0, acc[1][0], 0, 0, 0);
        acc[1][1] = __builtin_amdgcn_mfma_f32_16x16x32_bf16(a1, b1, acc[1][1], 0, 0, 0);
    }
}

// Swapped orientation: D[row=out-ch (mi,rg)][col=row-in-tile (ni,l16)]
template<int KD>
__device__ __forceinline__ void gemm_sw(const u16* act, const u16* __restrict__ wt,
                                        int w, int l16, int l4g, f32x4 (&acc)[2][2]) {
    const int RS = KD * 2;
#pragma unroll
    for (int k0 = 0; k0 < KD; k0 += 32) {
        const int kb = k0 * 2 + l4g * 16;
        bfrag wa0 = *(const bfrag*)((const char*)wt + (size_t)(32 * w + l16) * RS + kb);
        bfrag wa1 = *(const bfrag*)((const char*)wt + (size_t)(32 * w + 16 + l16) * RS + kb);
        bfrag be0 = *(const bfrag*)((const char*)act +
                    (unsigned)((l16 * RS + kb) ^ ((l16 & 7) << 4)));
        bfrag be1 = *(const bfrag*)((const char*)act +
                    (unsigned)(((16 + l16) * RS + kb) ^ ((l16 & 7) << 4)));
        acc[0][0] = __builtin_amdgcn_mfma_f32_16x16x32_bf16(wa0, be0, acc[0][0], 0, 0, 0);
        acc[0][1] = __builtin_amdgcn_mfma_f32_16x16x32_bf16(wa0, be1, acc[0][1], 0, 0, 0);
        acc[1][0] = __builtin_amdgcn_mfma_f32_16x16x32_bf16(wa1, be0, acc[1][0], 0, 0, 0);
        acc[1][1] = __builtin_amdgcn_mfma_f32_16x16x32_bf16(wa1, be1, acc[1][1], 0, 0, 0);
    }
}

// ---------------- edge kernel: persistent, single-barrier pipeline (round 13/15) ----------------
// Phase k (parity p): B1 -> reduce ev(T_{k-2}, red[p^1]) -> issue loads(T_{k+1})
//   -> GEMM1(T_k: a_sh[p] -> m1[p]) -> GEMM2(T_{k-1}: m1[p^1] -> g, red[p])
//   -> commit(T_{k+1} -> a_sh[p^1]).
// __launch_bounds__(256,2): compile budget; (256,3) spills weights (round 7).
// Residency pinned at 2 blocks/CU (rounds 9/14) -> grid MUST be 512.
__global__ void __launch_bounds__(256, 2)
egc_edge_csr(const u16* __restrict__ xb, const float* __restrict__ pos,
             const int* __restrict__ est_s, const int* __restrict__ eend_s,
             const u16* __restrict__ w1t, const float* __restrict__ w1last,
             const float* __restrict__ b1, const u16* __restrict__ w2t,
             const float* __restrict__ b2, const float* __restrict__ fw,
             const float* __restrict__ fb, u16* __restrict__ g,
             float* __restrict__ ev, int n_tiles)
{
    __shared__ __attribute__((aligned(16))) u16 a_sh[2][32 * 256];  // 32 KB dbuf, swz
    __shared__ __attribute__((aligned(16))) u16 m1_sh[2][32 * 128]; // 16 KB dbuf, swz
    __shared__ float red[2][32][17];                                // gate partials dbuf
    __shared__ float dist_l[2][32];

    const int t = threadIdx.x, lane = t & 63, w = t >> 6;
    const int l16 = lane & 15, l4g = lane >> 4;
    const unsigned swz = (unsigned)((l16 & 7) << 4);

    bfrag wa10[8], wa11[8], w2f0[4], w2f1[4];
#pragma unroll
    for (int i = 0; i < 8; ++i) {
        int kb = i * 64 + l4g * 16;
        wa10[i] = *(const bfrag*)((const char*)w1t + (size_t)(32 * w + l16) * 512 + kb);
        wa11[i] = *(const bfrag*)((const char*)w1t + (size_t)(32 * w + 16 + l16) * 512 + kb);
    }
#pragma unroll
    for (int i = 0; i < 4; ++i) {
        int kb = i * 64 + l4g * 16;
        w2f0[i] = *(const bfrag*)((const char*)w2t + (size_t)(32 * w + l16) * 256 + kb);
        w2f1[i] = *(const bfrag*)((const char*)w2t + (size_t)(32 * w + 16 + l16) * 256 + kb);
    }
    float w1l_r[2][4], b1_r[2][4], b2_r[2][4], fw_r[2][4];
#pragma unroll
    for (int mi = 0; mi < 2; ++mi)
#pragma unroll
        for (int rg = 0; rg < 4; ++rg) {
            int n = 32 * w + 16 * mi + l4g * 4 + rg;
            w1l_r[mi][rg] = w1last[n];
            b1_r[mi][rg]  = b1[n];
            b2_r[mi][rg]  = b2[n];
            fw_r[mi][rg]  = fw[n];
        }
    const float fbv = fb[0];

    float4 sv0, sv1, sv2, sv3;
    float pax = 0, pay = 0, paz = 0, pbx = 0, pby = 0, pbz = 0;

#define EDGE_ISSUE(TILE) do {                                                  \
        int e0_ = (TILE) * 32;                                                 \
        { int f_ = t;       int e_ = f_ >> 5, q_ = f_ & 31; int ge_ = e0_ + e_;\
          int nd_ = (q_ < 16) ? est_s[ge_] : eend_s[ge_];                      \
          sv0 = *(const float4*)(xb + (size_t)nd_ * 128 + (q_ & 15) * 8); }    \
        { int f_ = t + 256; int e_ = f_ >> 5, q_ = f_ & 31; int ge_ = e0_ + e_;\
          int nd_ = (q_ < 16) ? est_s[ge_] : eend_s[ge_];                      \
          sv1 = *(const float4*)(xb + (size_t)nd_ * 128 + (q_ & 15) * 8); }    \
        { int f_ = t + 512; int e_ = f_ >> 5, q_ = f_ & 31; int ge_ = e0_ + e_;\
          int nd_ = (q_ < 16) ? est_s[ge_] : eend_s[ge_];                      \
          sv2 = *(const float4*)(xb + (size_t)nd_ * 128 + (q_ & 15) * 8); }    \
        { int f_ = t + 768; int e_ = f_ >> 5, q_ = f_ & 31; int ge_ = e0_ + e_;\
          int nd_ = (q_ < 16) ? est_s[ge_] : eend_s[ge_];                      \
          sv3 = *(const float4*)(xb + (size_t)nd_ * 128 + (q_ & 15) * 8); }    \
        if (t < 32) {                                                          \
            int ge_ = e0_ + t;                                                 \
            int a_ = est_s[ge_], b_ = eend_s[ge_];                             \
            pax = pos[a_ * 3]; pay = pos[a_ * 3 + 1]; paz = pos[a_ * 3 + 2];   \
            pbx = pos[b_ * 3]; pby = pos[b_ * 3 + 1]; pbz = pos[b_ * 3 + 2];   \
        }                                                                      \
    } while (0)

#define EDGE_COMMIT(BUF) do {                                                  \
        { int f_ = t;       int e_ = f_ >> 5, q_ = f_ & 31;                    \
          unsigned by_ = (unsigned)(e_ * 512 + q_ * 16) ^ (unsigned)((e_ & 7) << 4); \
          *(float4*)((char*)a_sh[BUF] + by_) = sv0; }                          \
        { int f_ = t + 256; int e_ = f_ >> 5, q_ = f_ & 31;                    \
          unsigned by_ = (unsigned)(e_ * 512 + q_ * 16) ^ (unsigned)((e_ & 7) << 4); \
          *(float4*)((char*)a_sh[BUF] + by_) = sv1; }                          \
        { int f_ = t + 512; int e_ = f_ >> 5, q_ = f_ & 31;                    \
          unsigned by_ = (unsigned)(e_ * 512 + q_ * 16) ^ (unsigned)((e_ & 7) << 4); \
          *(float4*)((char*)a_sh[BUF] + by_) = sv2; }                          \
        { int f_ = t + 768; int e_ = f_ >> 5, q_ = f_ & 31;                    \
          unsigned by_ = (unsigned)(e_ * 512 + q_ * 16) ^ (unsigned)((e_ & 7) << 4); \
          *(float4*)((char*)a_sh[BUF] + by_) = sv3; }                          \
        if (t < 32) {                                                          \
            float dx_ = pax - pbx, dy_ = pay - pby, dz_ = paz - pbz;           \
            dx_ *= dx_; dy_ *= dy_; dz_ *= dz_;                                \
            dist_l[BUF][t] = sqrtf(dx_ * dx_ + dy_ * dy_ + dz_ * dz_);         \
        }                                                                      \
    } while (0)

    auto do_gemm1 = [&](int p) {
        f32x4 acc[2][2] = {};
#pragma unroll
        for (int i = 0; i < 8; ++i) {
            int kb = i * 64 + l4g * 16;
            bfrag be0 = *(const bfrag*)((const char*)a_sh[p] +
                        ((unsigned)(l16 * 512 + kb) ^ swz));
            bfrag be1 = *(const bfrag*)((const char*)a_sh[p] +
                        ((unsigned)((16 + l16) * 512 + kb) ^ swz));
            acc[0][0] = __builtin_amdgcn_mfma_f32_16x16x32_bf16(wa10[i], be0, acc[0][0], 0, 0, 0);
            acc[0][1] = __builtin_amdgcn_mfma_f32_16x16x32_bf16(wa10[i], be1, acc[0][1], 0, 0, 0);
            acc[1][0] = __builtin_amdgcn_mfma_f32_16x16x32_bf16(wa11[i], be0, acc[1][0], 0, 0, 0);
            acc[1][1] = __builtin_amdgcn_mfma_f32_16x16x32_bf16(wa11[i], be1, acc[1][1], 0, 0, 0);
        }
        float de0 = dist_l[p][l16];
        float de1 = dist_l[p][16 + l16];
#pragma unroll
        for (int mi = 0; mi < 2; ++mi)
#pragma unroll
            for (int ni = 0; ni < 2; ++ni) {
                float de = ni ? de1 : de0;
                u16x4 pk;
#pragma unroll
                for (int rg = 0; rg < 4; ++rg) {
                    float v = fast_tanh(acc[mi][ni][rg] + de * w1l_r[mi][rg] + b1_r[mi][rg]);
                    pk[rg] = f2b(v);
                }
                unsigned byte = ((unsigned)((16 * ni + l16) * 256 +
                                 (32 * w + 16 * mi + l4g * 4) * 2)) ^ swz;
                *(u16x4*)((char*)m1_sh[p] + byte) = pk;
            }
    };

    auto do_gemm2 = [&](int e0, int rp, int mp) {
        f32x4 acc[2][2] = {};
#pragma unroll
        for (int i = 0; i < 4; ++i) {
            int kb = i * 64 + l4g * 16;
            bfrag me0 = *(const bfrag*)((const char*)m1_sh[mp] +
                        ((unsigned)(l16 * 256 + kb) ^ swz));
            bfrag me1 = *(const bfrag*)((const char*)m1_sh[mp] +
                        ((unsigned)((16 + l16) * 256 + kb) ^ swz));
            acc[0][0] = __builtin_amdgcn_mfma_f32_16x16x32_bf16(w2f0[i], me0, acc[0][0], 0, 0, 0);
            acc[0][1] = __builtin_amdgcn_mfma_f32_16x16x32_bf16(w2f0[i], me1, acc[0][1], 0, 0, 0);
            acc[1][0] = __builtin_amdgcn_mfma_f32_16x16x32_bf16(w2f1[i], me0, acc[1][0], 0, 0, 0);
            acc[1][1] = __builtin_amdgcn_mfma_f32_16x16x32_bf16(w2f1[i], me1, acc[1][1], 0, 0, 0);
        }
        float part0 = 0.0f, part1 = 0.0f;
#pragma unroll
        for (int mi = 0; mi < 2; ++mi)
#pragma unroll
            for (int ni = 0; ni < 2; ++ni) {
                u16x4 pk;
                float ps = 0.0f;
#pragma unroll
                for (int rg = 0; rg < 4; ++rg) {
                    float v = fast_tanh(acc[mi][ni][rg] + b2_r[mi][rg]);
                    ps += v * fw_r[mi][rg];
                    pk[rg] = f2b(v);
                }
                if (ni) part1 += ps; else part0 += ps;
                int dstrow = e0 + 16 * ni + l16;        // CSR position = sequential
                *(u16x4*)(g + (size_t)dstrow * 128 + (32 * w + 16 * mi + l4g * 4)) = pk;
            }
        red[rp][l16][w * 4 + l4g]      = part0;
        red[rp][16 + l16][w * 4 + l4g] = part1;
    };

    auto do_reduce = [&](int e0, int rp) {
        if (t < 32) {
            float s = 0.0f;
#pragma unroll
            for (int j = 0; j < 16; ++j) s += red[rp][t][j];
            ev[e0 + t] = fast_tanh(s + fbv);
        }
    };

    int t1 = blockIdx.x;            // GEMM1 tile this phase
    int t2 = -1, tr = -1;           // GEMM2 tile / reduce tile
    int pk = 0;
    EDGE_ISSUE(t1);
    EDGE_COMMIT(0);
    int tnext = t1 + gridDim.x;

    while (true) {
        __syncthreads();                                 // B1 (one per tile)
        if (tr >= 0) do_reduce(tr * 32, pk ^ 1);
        bool have_next = (tnext < n_tiles);
        if (have_next) EDGE_ISSUE(tnext);
        do_gemm1(pk);
        if (t2 >= 0) do_gemm2(t2 * 32, pk, pk ^ 1);
        if (have_next) EDGE_COMMIT(pk ^ 1);
        tr = t2; t2 = t1;
        if (!have_next) break;
        t1 = tnext; tnext += gridDim.x; pk ^= 1;
    }
    // drain: GEMM2 for the last tile (m1 in m1_sh[pk]), plus two final reduces
    __syncthreads();
    if (tr >= 0) do_reduce(tr * 32, pk);
    do_gemm2(t2 * 32, pk ^ 1, pk);
    __syncthreads();
    do_reduce(t2 * 32, pk ^ 1);
#undef EDGE_ISSUE
#undef EDGE_COMMIT
}

// ---------------- gather: half-wave per edge parity, 4 edges in flight ----------------
__global__ void __launch_bounds__(256, 8)
gather_seq(const u16* __restrict__ g, const float* __restrict__ ev,
           const int* __restrict__ offs, u16* __restrict__ m_i)
{
    const int lane = threadIdx.x & 63;
    const int half = lane >> 5;
    const int l32  = lane & 31;
    const int n = blockIdx.x * 4 + (threadIdx.x >> 6);
    const int beg = offs[n], end = offs[n + 1];
    float a0 = 0.0f, a1 = 0.0f, a2 = 0.0f, a3 = 0.0f;
    float b0 = 0.0f, b1 = 0.0f, b2 = 0.0f, b3 = 0.0f;
    int e = beg + half;
    for (; e + 3 < end; e += 4) {
        uint2 v0 = *(const uint2*)(g + (size_t)e * 128 + l32 * 4);
        uint2 v1 = *(const uint2*)(g + (size_t)(e + 2) * 128 + l32 * 4);
        float e0 = ev[e], e1 = ev[e + 2];
        a0 += e0 * bits2f(v0.x << 16);
        a1 += e0 * bits2f(v0.x & 0xFFFF0000u);
        a2 += e0 * bits2f(v0.y << 16);
        a3 += e0 * bits2f(v0.y & 0xFFFF0000u);
        b0 += e1 * bits2f(v1.x << 16);
        b1 += e1 * bits2f(v1.x & 0xFFFF0000u);
        b2 += e1 * bits2f(v1.y << 16);
        b3 += e1 * bits2f(v1.y & 0xFFFF0000u);
    }
    for (; e < end; e += 2) {
        uint2 v0 = *(const uint2*)(g + (size_t)e * 128 + l32 * 4);
        float e0 = ev[e];
        a0 += e0 * bits2f(v0.x << 16);
        a1 += e0 * bits2f(v0.x & 0xFFFF0000u);
        a2 += e0 * bits2f(v0.y << 16);
        a3 += e0 * bits2f(v0.y & 0xFFFF0000u);
    }
    a0 += b0; a1 += b1; a2 += b2; a3 += b3;
    a0 += __shfl_xor(a0, 32);
    a1 += __shfl_xor(a1, 32);
    a2 += __shfl_xor(a2, 32);
    a3 += __shfl_xor(a3, 32);
    if (half == 0) {
        uint2 o;
        o.x = (unsigned)f2b(a0) | ((unsigned)f2b(a1) << 16);
        o.y = (unsigned)f2b(a2) | ((unsigned)f2b(a3) << 16);
        *(uint2*)(m_i + (size_t)n * 128 + l32 * 4) = o;
    }
}

// ---------------- edge kernel, fallback atomic path (round-3, proven) ----------------
__global__ void __launch_bounds__(256, 3)
egc_edge_mfma(const u16* __restrict__ xb, const float* __restrict__ pos,
              const int* __restrict__ est, const int* __restrict__ eend,
              const u16* __restrict__ w1t, const float* __restrict__ w1last,
              const float* __restrict__ b1, const u16* __restrict__ w2t,
              const float* __restrict__ b2, const float* __restrict__ fw,
              const float* __restrict__ fb, float* __restrict__ m_i)
{
    __shared__ __attribute__((aligned(16))) u16 a_sh[32 * 256];
    __shared__ __attribute__((aligned(16))) u16 m1_sh[32 * 128];
    __shared__ float m2_sh[32][132];
    __shared__ float dist_l[32];
    __shared__ float ev_l[32];
    __shared__ int   st_l[32];

    const int t = threadIdx.x;
    const int e0 = blockIdx.x * 32;
    const int lane = t & 63;
    const int w = t >> 6;
    const int l16 = lane & 15, l4g = lane >> 4;

#pragma unroll
    for (int i = 0; i < 4; ++i) {
        int f = t + 256 * i;
        int e = f >> 5, q = f & 31;
        int ge = e0 + e;
        int node = (q < 16) ? est[ge] : eend[ge];
        float4 v = *(const float4*)(xb + (size_t)node * 128 + (q & 15) * 8);
        unsigned byte = (unsigned)(e * 512 + q * 16) ^ (unsigned)((e & 7) << 4);
        *(float4*)((char*)a_sh + byte) = v;
    }
    if (t < 32) {
        int ge = e0 + t;
        int a = est[ge], b = eend[ge];
        st_l[t] = a;
        float dx = pos[a * 3 + 0] - pos[b * 3 + 0];
        float dy = pos[a * 3 + 1] - pos[b * 3 + 1];
        float dz = pos[a * 3 + 2] - pos[b * 3 + 2];
        dx *= dx; dy *= dy; dz *= dz;
        dist_l[t] = sqrtf(dx * dx + dy * dy + dz * dz);
    }
    __syncthreads();

    {
        f32x4 acc[2][2] = {};
        gemm_k<256>(a_sh, w1t, w, l16, l4g, acc);
#pragma unroll
        for (int mi = 0; mi < 2; ++mi)
#pragma unroll
            for (int ni = 0; ni < 2; ++ni) {
                const int col = 32 * w + 16 * ni + l16;
                const float wl = w1last[col], bb = b1[col];
#pragma unroll
                for (int rg = 0; rg < 4; ++rg) {
                    const int row = 16 * mi + l4g * 4 + rg;
                    float v = fast_tanh(acc[mi][ni][rg] + dist_l[row] * wl + bb);
                    unsigned byte = (unsigned)((row * 256 + col * 2) ^ ((row & 7) << 4));
                    *(u16*)((char*)m1_sh + byte) = f2b(v);
                }
            }
    }
    __syncthreads();

    {
        f32x4 acc[2][2] = {};
        gemm_k<128>(m1_sh, w2t, w, l16, l4g, acc);
#pragma unroll
        for (int mi = 0; mi < 2; ++mi)
#pragma unroll
            for (int ni = 0; ni < 2; ++ni) {
                const int col = 32 * w + 16 * ni + l16;
                const float bb = b2[col];
#pragma unroll
                for (int rg = 0; rg < 4; ++rg) {
                    const int row = 16 * mi + l4g * 4 + rg;
                    m2_sh[row][col] = fast_tanh(acc[mi][ni][rg] + bb);
                }
            }
    }
    __syncthreads();

    if (t < 128) {
        int e = t >> 2, p = t & 3;
        float s = 0.0f;
#pragma unroll
        for (int k = 0; k < 32; ++k) s += m2_sh[e][p * 32 + k] * fw[p * 32 + k];
        s += __shfl_xor(s, 1);
        s += __shfl_xor(s, 2);
        if (p == 0) ev_l[e] = fast_tanh(s + fb[0]);
    }
    __syncthreads();

    {
        int e = t >> 3, l8 = t & 7;
        float ev = ev_l[e];
        size_t base = (size_t)st_l[e] * HID + l8;
#pragma unroll
        for (int i = 0; i < 16; ++i)
            unsafeAtomicAdd(m_i + base + 8 * i, ev * m2_sh[e][l8 + 8 * i]);
    }
}

// ---------------- node kernel: swapped-operand layers, register l5 head ----------------
#define NODE_LAYER_SW(SRC, KD, WT, BIAS, DST, ACT)                             \
    {                                                                          \
        f32x4 acc[2][2] = {};                                                  \
        gemm_sw<KD>(SRC, WT, w, l16, l4g, acc);                                \
        float bbr[2][4];                                                       \
        _Pragma("unroll")                                                      \
        for (int mi = 0; mi < 2; ++mi)                                         \
            _Pragma("unroll")                                                  \
            for (int rg = 0; rg < 4; ++rg)                                     \
                bbr[mi][rg] = (BIAS)[32 * w + 16 * mi + l4g * 4 + rg];         \
        _Pragma("unroll")                                                      \
        for (int mi = 0; mi < 2; ++mi)                                         \
            _Pragma("unroll")                                                  \
            for (int ni = 0; ni < 2; ++ni) {                                   \
                const int node = 16 * ni + l16;                                \
                const int ch = 32 * w + 16 * mi + l4g * 4;                     \
                u16x4 pk;                                                      \
                _Pragma("unroll")                                              \
                for (int rg = 0; rg < 4; ++rg) {                               \
                    float v = acc[mi][ni][rg] + bbr[mi][rg];                   \
                    ACT;                                                       \
                    pk[rg] = f2b(v);                                           \
                }                                                              \
                unsigned byte = ((unsigned)(node * 256 + ch * 2)) ^ swz;       \
                *(u16x4*)((char*)(DST) + byte) = pk;                           \
            }                                                                  \
    }

// MODE 0: CSR path — m_i is bf16. MODE 1: fallback — m_i is fp32.
// LDS 38.9 KB, 4 blocks/CU (round 12). Residual read from a_sh's x half
// (intact when fh2 runs) — no global xf traffic (round 14, validated).
template<int MODE>
__global__ void __launch_bounds__(256, 4)
egc_node_mfma(const u16* __restrict__ xb,
              const void* __restrict__ m_i,
              const u16* __restrict__ fh1t, const float* __restrict__ hb1,
              const u16* __restrict__ fh2t, const float* __restrict__ hb2,
              const u16* __restrict__ l1t, const float* __restrict__ l1b,
              const u16* __restrict__ l2t, const float* __restrict__ l2b,
              const u16* __restrict__ l3t, const float* __restrict__ l3b,
              const u16* __restrict__ l4t, const float* __restrict__ l4b,
              const float* __restrict__ l5w, const float* __restrict__ l5b,
              float* __restrict__ out)
{
    __shared__ __attribute__((aligned(16))) u16 a_sh[32 * 256];   // 16 KB
    __shared__ __attribute__((aligned(16))) u16 bA[32 * 128];     // 8 KB
    __shared__ __attribute__((aligned(16))) u16 bB[32 * 128];     // 8 KB
    __shared__ float red[32][3][17];                              // 6.4 KB l5 partials

    const int t = threadIdx.x;
    const int n0 = blockIdx.x * 32;
    const int lane = t & 63;
    const int w = t >> 6;
    const int l16 = lane & 15, l4g = lane >> 4;
    const unsigned swz = (unsigned)((l16 & 7) << 4);

#pragma unroll
    for (int i = 0; i < 2; ++i) {
        int f = t + 256 * i;
        int n = f >> 4, q = f & 15;
        float4 v = *(const float4*)(xb + (size_t)(n0 + n) * 128 + q * 8);
        unsigned byte = (unsigned)((n * 512 + q * 16) ^ ((n & 7) << 4));
        *(float4*)((char*)a_sh + byte) = v;
    }
    if (MODE == 0) {
#pragma unroll
        for (int i = 0; i < 2; ++i) {
            int f = t + 256 * i;
            int n = f >> 4, q = f & 15;
            float4 v = *(const float4*)((const u16*)m_i + (size_t)(n0 + n) * 128 + q * 8);
            unsigned byte = (unsigned)((n * 512 + 256 + q * 16) ^ ((n & 7) << 4));
            *(float4*)((char*)a_sh + byte) = v;
        }
    } else {
#pragma unroll
        for (int i = 0; i < 2; ++i) {
            int f = t + 256 * i;
            int n = f >> 4, q = f & 15;
            const float* src = (const float*)m_i + (size_t)(n0 + n) * 128 + q * 8;
            float4 v0 = *(const float4*)(src);
            float4 v1 = *(const float4*)(src + 4);
            u16x8 o = { f2b(v0.x), f2b(v0.y), f2b(v0.z), f2b(v0.w),
                        f2b(v1.x), f2b(v1.y), f2b(v1.z), f2b(v1.w) };
            unsigned byte = (unsigned)((n * 512 + 256 + q * 16) ^ ((n & 7) << 4));
            *(u16x8*)((char*)a_sh + byte) = o;
        }
    }
    __syncthreads();

    NODE_LAYER_SW(a_sh, 256, fh1t, hb1, bA, { v = fast_tanh(v); })
    __syncthreads();

    // fh2: K=128, + residual from a_sh's x half (bf16, swizzled 8 B read) -> bB
    {
        f32x4 acc[2][2] = {};
        gemm_sw<128>(bA, fh2t, w, l16, l4g, acc);
        float bbr[2][4];
#pragma unroll
        for (int mi = 0; mi < 2; ++mi)
#pragma unroll
            for (int rg = 0; rg < 4; ++rg)
                bbr[mi][rg] = hb2[32 * w + 16 * mi + l4g * 4 + rg];
#pragma unroll
        for (int mi = 0; mi < 2; ++mi)
#pragma unroll
            for (int ni = 0; ni < 2; ++ni) {
                const int node = 16 * ni + l16;
                const int ch = 32 * w + 16 * mi + l4g * 4;
                unsigned rb = ((unsigned)(node * 512 + ch * 2)) ^
                              ((unsigned)((node & 7) << 4));
                u16x4 xr = *(const u16x4*)((const char*)a_sh + rb);
                u16x4 pk;
                pk[0] = f2b(acc[mi][ni][0] + bbr[mi][0] + b2f(xr[0]));
                pk[1] = f2b(acc[mi][ni][1] + bbr[mi][1] + b2f(xr[1]));
                pk[2] = f2b(acc[mi][ni][2] + bbr[mi][2] + b2f(xr[2]));
                pk[3] = f2b(acc[mi][ni][3] + bbr[mi][3] + b2f(xr[3]));
                unsigned byte = ((unsigned)(node * 256 + ch * 2)) ^ swz;
                *(u16x4*)((char*)bB + byte) = pk;
            }
    }
    __syncthreads();

    NODE_LAYER_SW(bB, 128, l1t, l1b, bA, { v = v > 0.0f ? v : 0.01f * v; })
    __syncthreads();
    NODE_LAYER_SW(bA, 128, l2t, l2b, bB, { v = v > 0.0f ? v : 0.01f * v; })
    __syncthreads();
    NODE_LAYER_SW(bB, 128, l3t, l3b, bA, { v = v > 0.0f ? v : 0.01f * v; })
    __syncthreads();

    // l4: K=128 -> lrelu -> l5 partials in registers -> red
    {
        f32x4 acc[2][2] = {};
        gemm_sw<128>(bA, l4t, w, l16, l4g, acc);
        float bbr[2][4], w5[2][4][3];
#pragma unroll
        for (int mi = 0; mi < 2; ++mi)
#pragma unroll
            for (int rg = 0; rg < 4; ++rg) {
                int ch = 32 * w + 16 * mi + l4g * 4 + rg;
                bbr[mi][rg] = l4b[ch];
#pragma unroll
                for (int cc = 0; cc < 3; ++cc) w5[mi][rg][cc] = l5w[ch * 3 + cc];
            }
#pragma unroll
        for (int ni = 0; ni < 2; ++ni) {
            float p0 = 0.0f, p1 = 0.0f, p2 = 0.0f;
#pragma unroll
            for (int mi = 0; mi < 2; ++mi)
#pragma unroll
                for (int rg = 0; rg < 4; ++rg) {
                    float v = acc[mi][ni][rg] + bbr[mi][rg];
                    v = v > 0.0f ? v : 0.01f * v;
                    p0 += v * w5[mi][rg][0];
                    p1 += v * w5[mi][rg][1];
                    p2 += v * w5[mi][rg][2];
                }
            const int n = 16 * ni + l16, j = w * 4 + l4g;
            red[n][0][j] = p0;
            red[n][1][j] = p1;
            red[n][2][j] = p2;
        }
    }
    __syncthreads();

    if (t < 96) {
        int n = t / 3, cc = t % 3;
        float s = l5b[cc];
#pragma unroll
        for (int j = 0; j < 16; ++j) s += red[n][cc][j];
        out[(size_t)(n0 + n) * 3 + cc] = s;
    }
}

extern "C" void kernel_launch(void* const* d_in, const int* in_sizes, int n_in,
                              void* d_out, int out_size, void* d_ws, size_t ws_size,
                              hipStream_t stream)
{
    const float* x      = (const float*)d_in[0];
    const float* pos    = (const float*)d_in[1];
    const int*   eidx   = (const int*)d_in[2];
    const float* fe_w1  = (const float*)d_in[3];
    const float* fe_b1  = (const float*)d_in[4];
    const float* fe_w2  = (const float*)d_in[5];
    const float* fe_b2  = (const float*)d_in[6];
    const float* finf_w = (const float*)d_in[7];
    const float* finf_b = (const float*)d_in[8];
    const float* fh_w1  = (const float*)d_in[9];
    const float* fh_b1  = (const float*)d_in[10];
    const float* fh_w2  = (const float*)d_in[11];
    const float* fh_b2  = (const float*)d_in[12];
    const float* l1w    = (const float*)d_in[13];
    const float* l1b    = (const float*)d_in[14];
    const float* l2w    = (const float*)d_in[15];
    const float* l2b    = (const float*)d_in[16];
    const float* l3w    = (const float*)d_in[17];
    const float* l3b    = (const float*)d_in[18];
    const float* l4w    = (const float*)d_in[19];
    const float* l4b    = (const float*)d_in[20];
    const float* l5w    = (const float*)d_in[21];
    const float* l5b    = (const float*)d_in[22];
    float* out = (float*)d_out;

    const int n_edges = in_sizes[2] / 2;             // 600000
    const int n_nodes = in_sizes[0] / HID;           // 100000
    const int nsb     = (n_nodes + 255) / 256;       // 391 scan blocks
    const int n_tiles = n_edges / 32;                // 18750
    const int nxb     = (n_nodes * HID) / (256 * 8); // 6250 prep_x blocks
    const int nhb     = (n_edges + 255) / 256;       // 2344 hist blocks

    char* ws = (char*)d_ws;
    const bool use_csr = (ws_size >= 208800000ULL);

    if (use_csr) {
        u16* g     = (u16*)(ws + 0);                 // 153,600,000 B
        u16* xb    = (u16*)(ws + 153600000);         //  25,600,000 B
        u16* m_i   = (u16*)(ws + 179200000);         //  25,600,000 B (bf16)
        int* est_s  = (int*)(ws + 179200000);        //   2,400,000 B (overlay, dead before m_i)
        int* eend_s = (int*)(ws + 181600000);        //   2,400,000 B
        u16* w1t  = (u16*)(ws + 204800000);
        u16* w2t  = (u16*)(ws + 204865536);
        u16* fh1t = (u16*)(ws + 204898304);
        u16* fh2t = (u16*)(ws + 204963840);
        u16* l1t  = (u16*)(ws + 204996608);
        u16* l2t  = (u16*)(ws + 205029376);
        u16* l3t  = (u16*)(ws + 205062144);
        u16* l4t  = (u16*)(ws + 205094912);
        int* cnt  = (int*)(ws + 205127680);          // 400,000 B
        int* offs = (int*)(ws + 205527680);          // 400,016 B (N+1 ints)
        int* cur  = (int*)(ws + 205927696);          // 400,000 B
        float* ev = (float*)(ws + 206327696);        // 2,400,000 B
        int* part = (int*)(ws + 208727696);          // scan partials

        (void)hipMemsetAsync(cnt, 0, (size_t)n_nodes * sizeof(int), stream);
        prep_combo<<<dim3(nxb + 640 + nhb), dim3(256), 0, stream>>>(
            x, xb, fe_w1, fh_w1, fe_w2, fh_w2, l1w, l2w, l3w, l4w,
            w1t, fh1t, w2t, fh2t, l1t, l2t, l3t, l4t, eidx, cnt, n_edges, nxb);

        scan1<<<dim3(nsb), dim3(256), 0, stream>>>(cnt, cnt, part, n_nodes);
        scan3<<<dim3(nsb), dim3(256), 0, stream>>>(cnt, part, offs, cur, n_nodes, n_edges);
        reorder_kernel<<<dim3(nhb), dim3(256), 0, stream>>>(
            eidx, eidx + n_edges, cur, est_s, eend_s, n_edges);

        egc_edge_csr<<<dim3(512), dim3(256), 0, stream>>>(
            xb, pos, est_s, eend_s, w1t, fe_w1 + (size_t)256 * HID, fe_b1,
            w2t, fe_b2, finf_w, finf_b, g, ev, n_tiles);

        gather_seq<<<dim3(n_nodes / 4), dim3(256), 0, stream>>>(g, ev, offs, m_i);

        egc_node_mfma<0><<<dim3(n_nodes / 32), dim3(256), 0, stream>>>(
            xb, m_i, fh1t, fh_b1, fh2t, fh_b2, l1t, l1b, l2t, l2b,
            l3t, l3b, l4t, l4b, l5w, l5b, out);
    } else {
        // fallback: round-3 fused atomic path
        float* m_i = (float*)(ws + 0);
        u16* xb    = (u16*)(ws + 51200000);
        u16* w1t   = (u16*)(ws + 76800000);
        u16* w2t   = (u16*)(ws + 76865536);
        u16* fh1t  = (u16*)(ws + 76898304);
        u16* fh2t  = (u16*)(ws + 76963840);
        u16* l1t   = (u16*)(ws + 76996608);
        u16* l2t   = (u16*)(ws + 77029376);
        u16* l3t   = (u16*)(ws + 77062144);
        u16* l4t   = (u16*)(ws + 77094912);

        (void)hipMemsetAsync(m_i, 0, (size_t)n_nodes * HID * sizeof(float), stream);
        prep_combo<<<dim3(nxb + 640), dim3(256), 0, stream>>>(
            x, xb, fe_w1, fh_w1, fe_w2, fh_w2, l1w, l2w, l3w, l4w,
            w1t, fh1t, w2t, fh2t, l1t, l2t, l3t, l4t, eidx, (int*)d_ws, 0, nxb);

        egc_edge_mfma<<<dim3(n_edges / 32), dim3(256), 0, stream>>>(
            xb, pos, eidx, eidx + n_edges, w1t, fe_w1 + (size_t)256 * HID, fe_b1,
            w2t, fe_b2, finf_w, finf_b, m_i);

        egc_node_mfma<1><<<dim3(n_nodes / 32), dim3(256), 0, stream>>>(
            xb, m_i, fh1t, fh_b1, fh2t, fh_b2, l1t, l1b, l2t, l2b,
            l3t, l3b, l4t, l4b, l5w, l5b, out);
    }
}